// Round 1
// baseline (468.316 us; speedup 1.0000x reference)
//
#include <hip/hip_runtime.h>
#include <hip/hip_bf16.h>
#include <stdint.h>

typedef float   f32x4  __attribute__((ext_vector_type(4)));
typedef __bf16  bf16x8 __attribute__((ext_vector_type(8)));
typedef unsigned short u16x4 __attribute__((ext_vector_type(4)));
typedef unsigned short u16x8 __attribute__((ext_vector_type(8)));

__device__ __forceinline__ uint16_t f2b(float x) {
  union { float f; uint32_t u; } c; c.f = x;
  uint32_t u = c.u;
  return (uint16_t)((u + 0x7FFFu + ((u >> 16) & 1u)) >> 16);
}

__device__ __forceinline__ f32x4 mfma32(bf16x8 a, bf16x8 b, f32x4 c) {
  return __builtin_amdgcn_mfma_f32_16x16x32_bf16(a, b, c, 0, 0, 0);
}

#define GLDS16(g, l) __builtin_amdgcn_global_load_lds( \
    (const __attribute__((address_space(1))) void*)(const void*)(g), \
    (__attribute__((address_space(3))) void*)(void*)(l), 16, 0, 0)

// ---------------- fp32 -> bf16 convert ----------------
__global__ __launch_bounds__(256) void f2b_k(const float* __restrict__ in,
                                             uint16_t* __restrict__ out, int n) {
  int i = (blockIdx.x * 256 + threadIdx.x) * 4;
  if (i >= n) return;
  f32x4 v = *(const f32x4*)(in + i);
  u16x4 o;
  o[0] = f2b(v[0]); o[1] = f2b(v[1]); o[2] = f2b(v[2]); o[3] = f2b(v[3]);
  *(u16x4*)(out + i) = o;
}

// ---------------- weight transpose: W (1024 x 1024, KxN) -> WT (NxK) bf16 ----------------
__global__ __launch_bounds__(256) void wtrans_k(const float* __restrict__ W,
                                                uint16_t* __restrict__ WT) {
  __shared__ float tl[32][33];
  const int n0 = blockIdx.x * 32, k0 = blockIdx.y * 32;
  const int tx = threadIdx.x, ty = threadIdx.y; // (32, 8)
#pragma unroll
  for (int i = 0; i < 32; i += 8)
    tl[ty + i][tx] = W[(size_t)(k0 + ty + i) * 1024 + n0 + tx];
  __syncthreads();
#pragma unroll
  for (int i = 0; i < 32; i += 8)
    WT[(size_t)(n0 + ty + i) * 1024 + k0 + tx] = f2b(tl[tx][ty + i]);
}

// ---------------- V transpose: qkv (2048x3072) v-slice -> vT[(b*16+h)*64+d][s] ----------------
__global__ __launch_bounds__(256) void vtrans_k(const uint16_t* __restrict__ qkv,
                                                uint16_t* __restrict__ vT) {
  int idx = blockIdx.x * 256 + threadIdx.x;   // 0 .. 2M-1
  int s  = idx & 1023;
  int r  = idx >> 10;
  int d  = r & 63;
  int bh = r >> 6;
  int b = bh >> 4, h = bh & 15;
  vT[idx] = qkv[(size_t)(b * 1024 + s) * 3072 + 2048 + h * 64 + d];
}

// ---------------- GEMM: C = A(bf16, M x 1024) * BT(bf16, N x 1024)^T + bias [+res/gelu] ----------------
enum { EPI_BF16 = 0, EPI_RES = 1, EPI_GELU = 2 };

template<int EPI>
__global__ __launch_bounds__(256) void gemm_k(
    const uint16_t* __restrict__ A, int lda,
    const uint16_t* __restrict__ BT,
    const float* __restrict__ bias,
    const float* __restrict__ res,
    void* __restrict__ Cv, int ldc) {
  __shared__ uint16_t As[128 * 32];
  __shared__ uint16_t Bs[128 * 32];
  const int t = threadIdx.x;
  const int lane = t & 63, w = t >> 6;
  const int wr = w >> 1, wc = w & 1;
  const int l15 = lane & 15, g = lane >> 4;
  const int bm0 = blockIdx.y * 128, bn0 = blockIdx.x * 128;

  const uint16_t* ga = A  + (size_t)(bm0 + (t >> 2)) * lda  + (t & 3) * 8;
  const uint16_t* gb = BT + (size_t)(bn0 + (t >> 2)) * 1024 + (t & 3) * 8;

  f32x4 acc[4][4] = {};

  for (int k0 = 0; k0 < 1024; k0 += 32) {
    __syncthreads();
    GLDS16(ga + k0,                     &As[t * 8]);
    GLDS16(ga + (size_t)64 * lda + k0,  &As[2048 + t * 8]);
    GLDS16(gb + k0,                     &Bs[t * 8]);
    GLDS16(gb + 64 * 1024 + k0,         &Bs[2048 + t * 8]);
    __syncthreads();
    bf16x8 af[4], bf[4];
#pragma unroll
    for (int i = 0; i < 4; i++)
      af[i] = *(const bf16x8*)&As[(wr * 64 + i * 16 + l15) * 32 + g * 8];
#pragma unroll
    for (int i = 0; i < 4; i++)
      bf[i] = *(const bf16x8*)&Bs[(wc * 64 + i * 16 + l15) * 32 + g * 8];
#pragma unroll
    for (int mi = 0; mi < 4; mi++)
#pragma unroll
      for (int ni = 0; ni < 4; ni++)
        acc[mi][ni] = mfma32(af[mi], bf[ni], acc[mi][ni]);
  }

#pragma unroll
  for (int mi = 0; mi < 4; mi++) {
#pragma unroll
    for (int ni = 0; ni < 4; ni++) {
      const int row0 = bm0 + wr * 64 + mi * 16 + g * 4;
      const int col  = bn0 + wc * 64 + ni * 16 + l15;
      const float bc = bias[col];
#pragma unroll
      for (int r = 0; r < 4; r++) {
        float v = acc[mi][ni][r] + bc;
        const size_t idx = (size_t)(row0 + r) * ldc + col;
        if constexpr (EPI == EPI_RES) {
          ((float*)Cv)[idx] = v + res[idx];
        } else if constexpr (EPI == EPI_GELU) {
          float gl = 0.5f * v * (1.0f + erff(v * 0.70710678118654752f));
          ((uint16_t*)Cv)[idx] = f2b(gl);
        } else {
          ((uint16_t*)Cv)[idx] = f2b(v);
        }
      }
    }
  }
}

// ---------------- fused 3-branch max-softmax attention ----------------
// grid (S/64, H, B), 256 threads = 4 waves; wave w owns q rows q0..q0+15.
// Pass 1: Z_b per q row (no max-sub needed: |logit*scale| << 1).
// Pass 2: recompute logits, P = max_b exp(s_b)/Z_b, PV accumulated as O^T via
// in-register fragment assembly (contraction-slot permutation; V read permuted).
__global__ __launch_bounds__(256) void attn_k(
    const uint16_t* __restrict__ qkv,
    const uint16_t* __restrict__ sqk0,
    const uint16_t* __restrict__ sqk1,
    const uint16_t* __restrict__ vT,
    uint16_t* __restrict__ O) {
  const int t = threadIdx.x;
  const int lane = t & 63, w = t >> 6;
  const int l15 = lane & 15, g = lane >> 4;
  const int h = blockIdx.y, b = blockIdx.z;
  const int q0 = blockIdx.x * 64 + w * 16;
  const float scale = 0.03125f;  // 1/sqrt(1024)
  const size_t rq = (size_t)(b * 1024 + q0 + l15);

  bf16x8 qf[3][2];
  {
    const uint16_t* p = qkv + rq * 3072 + h * 64 + g * 8;
    qf[0][0] = *(const bf16x8*)p; qf[0][1] = *(const bf16x8*)(p + 32);
    p = sqk0 + rq * 2048 + h * 64 + g * 8;
    qf[1][0] = *(const bf16x8*)p; qf[1][1] = *(const bf16x8*)(p + 32);
    p = sqk1 + rq * 2048 + h * 64 + g * 8;
    qf[2][0] = *(const bf16x8*)p; qf[2][1] = *(const bf16x8*)(p + 32);
  }
  const uint16_t* kb0 = qkv  + (size_t)b * 1024 * 3072 + 1024 + h * 64 + g * 8;
  const uint16_t* kb1 = sqk0 + (size_t)b * 1024 * 2048 + 1024 + h * 64 + g * 8;
  const uint16_t* kb2 = sqk1 + (size_t)b * 1024 * 2048 + 1024 + h * 64 + g * 8;

  // ---- pass 1: Z per branch per q row ----
  float z0 = 0.f, z1 = 0.f, z2 = 0.f;
  for (int kt = 0; kt < 64; kt++) {
    const int kr = kt * 16 + l15;
    const uint16_t* p0 = kb0 + (size_t)kr * 3072;
    const uint16_t* p1 = kb1 + (size_t)kr * 2048;
    const uint16_t* p2 = kb2 + (size_t)kr * 2048;
    f32x4 c0 = {}, c1 = {}, c2 = {};
    c0 = mfma32(*(const bf16x8*)p0,        qf[0][0], c0);
    c0 = mfma32(*(const bf16x8*)(p0 + 32), qf[0][1], c0);
    c1 = mfma32(*(const bf16x8*)p1,        qf[1][0], c1);
    c1 = mfma32(*(const bf16x8*)(p1 + 32), qf[1][1], c1);
    c2 = mfma32(*(const bf16x8*)p2,        qf[2][0], c2);
    c2 = mfma32(*(const bf16x8*)(p2 + 32), qf[2][1], c2);
#pragma unroll
    for (int r = 0; r < 4; r++) {
      z0 += __expf(c0[r] * scale);
      z1 += __expf(c1[r] * scale);
      z2 += __expf(c2[r] * scale);
    }
  }
  z0 += __shfl_xor(z0, 16, 64); z0 += __shfl_xor(z0, 32, 64);
  z1 += __shfl_xor(z1, 16, 64); z1 += __shfl_xor(z1, 32, 64);
  z2 += __shfl_xor(z2, 16, 64); z2 += __shfl_xor(z2, 32, 64);
  const float rz0 = 1.0f / z0, rz1 = 1.0f / z1, rz2 = 1.0f / z2;

  // ---- pass 2: P = max_b softmax_b, O^T += V^T * P^T ----
  f32x4 accO[4] = {};
  const uint16_t* vb = vT + ((size_t)(b * 16 + h) * 64 + l15) * 1024 + g * 4;

  for (int kt2 = 0; kt2 < 32; kt2++) {
    u16x8 pu;
#pragma unroll
    for (int sub = 0; sub < 2; sub++) {
      const int kr = kt2 * 32 + sub * 16 + l15;
      const uint16_t* p0 = kb0 + (size_t)kr * 3072;
      const uint16_t* p1 = kb1 + (size_t)kr * 2048;
      const uint16_t* p2 = kb2 + (size_t)kr * 2048;
      f32x4 c0 = {}, c1 = {}, c2 = {};
      c0 = mfma32(*(const bf16x8*)p0,        qf[0][0], c0);
      c0 = mfma32(*(const bf16x8*)(p0 + 32), qf[0][1], c0);
      c1 = mfma32(*(const bf16x8*)p1,        qf[1][0], c1);
      c1 = mfma32(*(const bf16x8*)(p1 + 32), qf[1][1], c1);
      c2 = mfma32(*(const bf16x8*)p2,        qf[2][0], c2);
      c2 = mfma32(*(const bf16x8*)(p2 + 32), qf[2][1], c2);
#pragma unroll
      for (int r = 0; r < 4; r++) {
        float p0v = __expf(c0[r] * scale) * rz0;
        float p1v = __expf(c1[r] * scale) * rz1;
        float p2v = __expf(c2[r] * scale) * rz2;
        pu[sub * 4 + r] = f2b(fmaxf(fmaxf(p0v, p1v), p2v));
      }
    }
    const bf16x8 pf = __builtin_bit_cast(bf16x8, pu);
#pragma unroll
    for (int dt = 0; dt < 4; dt++) {
      const uint16_t* vp = vb + (size_t)dt * 16 * 1024 + kt2 * 32;
      u16x4 lo = *(const u16x4*)vp;
      u16x4 hi = *(const u16x4*)(vp + 16);
      u16x8 vv = __builtin_shufflevector(lo, hi, 0, 1, 2, 3, 4, 5, 6, 7);
      accO[dt] = mfma32(__builtin_bit_cast(bf16x8, vv), pf, accO[dt]);
    }
  }

  uint16_t* ob = O + rq * 1024 + h * 64;
#pragma unroll
  for (int dt = 0; dt < 4; dt++)
#pragma unroll
    for (int r = 0; r < 4; r++)
      ob[dt * 16 + g * 4 + r] = f2b(accO[dt][r]);
}

// ---------------- LayerNorm over rows of 1024 fp32, optional bf16 copy ----------------
template<int WB>
__global__ __launch_bounds__(256) void ln_k(const float* __restrict__ X,
                                            const float* __restrict__ G,
                                            const float* __restrict__ Bt,
                                            float* __restrict__ Yf,
                                            uint16_t* __restrict__ Yb) {
  const int row = blockIdx.x, t = threadIdx.x;
  const int lane = t & 63, w = t >> 6;
  const size_t base = (size_t)row * 1024 + t * 4;
  f32x4 x = *(const f32x4*)(X + base);
  float s  = x[0] + x[1] + x[2] + x[3];
  float s2 = x[0] * x[0] + x[1] * x[1] + x[2] * x[2] + x[3] * x[3];
#pragma unroll
  for (int o = 1; o < 64; o <<= 1) {
    s  += __shfl_xor(s,  o, 64);
    s2 += __shfl_xor(s2, o, 64);
  }
  __shared__ float red[8];
  if (lane == 0) { red[w] = s; red[4 + w] = s2; }
  __syncthreads();
  s  = red[0] + red[1] + red[2] + red[3];
  s2 = red[4] + red[5] + red[6] + red[7];
  const float mean = s * (1.0f / 1024.0f);
  const float rstd = rsqrtf(s2 * (1.0f / 1024.0f) - mean * mean + 1e-5f);
  f32x4 gv = *(const f32x4*)(G + t * 4);
  f32x4 bv = *(const f32x4*)(Bt + t * 4);
  f32x4 y;
#pragma unroll
  for (int i = 0; i < 4; i++) y[i] = (x[i] - mean) * rstd * gv[i] + bv[i];
  *(f32x4*)(Yf + base) = y;
  if constexpr (WB) {
    u16x4 o;
#pragma unroll
    for (int i = 0; i < 4; i++) o[i] = f2b(y[i]);
    *(u16x4*)(Yb + base) = o;
  }
}

// ---------------- host ----------------
extern "C" void kernel_launch(void* const* d_in, const int* in_sizes, int n_in,
                              void* d_out, int out_size, void* d_ws, size_t ws_size,
                              hipStream_t stream) {
  (void)in_sizes; (void)n_in; (void)out_size;
  const float* id_x = (const float*)d_in[0];
  const float* side = (const float*)d_in[1];
  const float* Wq  = (const float*)d_in[3];
  const float* bq  = (const float*)d_in[4];
  const float* Wk  = (const float*)d_in[5];
  const float* bk  = (const float*)d_in[6];
  const float* Wv  = (const float*)d_in[7];
  const float* bv  = (const float*)d_in[8];
  const float* sWq = (const float*)d_in[9];
  const float* sbq = (const float*)d_in[10];
  const float* sWk = (const float*)d_in[11];
  const float* sbk = (const float*)d_in[12];
  const float* Wo  = (const float*)d_in[13];
  const float* bo  = (const float*)d_in[14];
  const float* W1  = (const float*)d_in[15];
  const float* b1  = (const float*)d_in[16];
  const float* W2  = (const float*)d_in[17];
  const float* b2  = (const float*)d_in[18];
  const float* g1  = (const float*)d_in[19];
  const float* be1 = (const float*)d_in[20];
  const float* g2  = (const float*)d_in[21];
  const float* be2 = (const float*)d_in[22];

  char* ws = (char*)d_ws;
  const size_t oWT   = 0;                       // 10240x1024 bf16 = 20,971,520
  const size_t oBias = oWT + 20971520;          // 7168 f32 = 28,672
  const size_t oC    = oBias + 28672;           // 4 MB: xb, later Ob
  const size_t oD    = oC + 4194304;            // 8 MB: sdb
  const size_t oE    = oD + 8388608;            // 32 MB region
  const size_t total = oE + 33554432;           // 67,137,536
  if (ws_size < total) return;

  uint16_t* WT    = (uint16_t*)(ws + oWT);
  float*    biasc = (float*)(ws + oBias);
  uint16_t* xb    = (uint16_t*)(ws + oC);
  uint16_t* Ob    = (uint16_t*)(ws + oC);          // aliases xb (dead)
  uint16_t* sdb   = (uint16_t*)(ws + oD);
  char* E = ws + oE;
  uint16_t* qkv  = (uint16_t*)(E);                  // 12 MB
  uint16_t* sqk0 = (uint16_t*)(E + 12582912);       // 8 MB
  uint16_t* sqk1 = (uint16_t*)(E + 20971520);       // 8 MB
  uint16_t* vTp  = (uint16_t*)(E + 29360128);       // 4 MB
  // post-attention aliases (qkv/sqk/vT all dead after attn_k):
  float*    x1   = (float*)(E);                     // 8 MB
  float*    x1n  = (float*)(E + 8388608);           // 8 MB
  uint16_t* x1nb = (uint16_t*)(E + 16777216);       // 4 MB
  uint16_t* hb   = (uint16_t*)(E + 20971520 + 0);   // 4 MB (sqk1 region)
  float*    x2   = (float*)(E + 25165824);          // 8 MB

  // bias concat: [bq|bk|bv] , [sbq0|sbk0] , [sbq1|sbk1]
  hipMemcpyAsync(biasc + 0,    bq,        4096, hipMemcpyDeviceToDevice, stream);
  hipMemcpyAsync(biasc + 1024, bk,        4096, hipMemcpyDeviceToDevice, stream);
  hipMemcpyAsync(biasc + 2048, bv,        4096, hipMemcpyDeviceToDevice, stream);
  hipMemcpyAsync(biasc + 3072, sbq,       4096, hipMemcpyDeviceToDevice, stream);
  hipMemcpyAsync(biasc + 4096, sbk,       4096, hipMemcpyDeviceToDevice, stream);
  hipMemcpyAsync(biasc + 5120, sbq + 1024, 4096, hipMemcpyDeviceToDevice, stream);
  hipMemcpyAsync(biasc + 6144, sbk + 1024, 4096, hipMemcpyDeviceToDevice, stream);

  dim3 tb(32, 8), tg(32, 32);
  wtrans_k<<<tg, tb, 0, stream>>>(Wq,              WT + 0);
  wtrans_k<<<tg, tb, 0, stream>>>(Wk,              WT + 1048576);
  wtrans_k<<<tg, tb, 0, stream>>>(Wv,              WT + 2097152);
  wtrans_k<<<tg, tb, 0, stream>>>(sWq,             WT + 3145728);
  wtrans_k<<<tg, tb, 0, stream>>>(sWk,             WT + 4194304);
  wtrans_k<<<tg, tb, 0, stream>>>(sWq + 1048576,   WT + 5242880);
  wtrans_k<<<tg, tb, 0, stream>>>(sWk + 1048576,   WT + 6291456);
  wtrans_k<<<tg, tb, 0, stream>>>(Wo,              WT + 7340032);
  wtrans_k<<<tg, tb, 0, stream>>>(W1,              WT + 8388608);
  wtrans_k<<<tg, tb, 0, stream>>>(W2,              WT + 9437184);

  f2b_k<<<2048, 256, 0, stream>>>(id_x, xb, 2097152);
  f2b_k<<<4096, 256, 0, stream>>>(side, sdb, 4194304);

  gemm_k<EPI_BF16><<<dim3(24, 16), 256, 0, stream>>>(xb, 1024, WT,           biasc,        nullptr, qkv,  3072);
  gemm_k<EPI_BF16><<<dim3(16, 16), 256, 0, stream>>>(sdb, 2048, WT + 3145728, biasc + 3072, nullptr, sqk0, 2048);
  gemm_k<EPI_BF16><<<dim3(16, 16), 256, 0, stream>>>(sdb + 1024, 2048, WT + 5242880, biasc + 5120, nullptr, sqk1, 2048);

  vtrans_k<<<8192, 256, 0, stream>>>(qkv, vTp);
  attn_k<<<dim3(16, 16, 2), 256, 0, stream>>>(qkv, sqk0, sqk1, vTp, Ob);

  gemm_k<EPI_RES><<<dim3(8, 16), 256, 0, stream>>>(Ob, 1024, WT + 7340032, bo, id_x, x1, 1024);
  ln_k<1><<<2048, 256, 0, stream>>>(x1, g1, be1, x1n, x1nb);
  gemm_k<EPI_GELU><<<dim3(8, 16), 256, 0, stream>>>(x1nb, 1024, WT + 8388608, b1, nullptr, hb, 1024);
  gemm_k<EPI_RES><<<dim3(8, 16), 256, 0, stream>>>(hb, 1024, WT + 9437184, b2, x1n, x2, 1024);
  ln_k<0><<<2048, 256, 0, stream>>>(x2, g2, be2, (float*)d_out, nullptr);
}

// Round 2
// 297.149 us; speedup vs baseline: 1.5760x; 1.5760x over previous
//
#include <hip/hip_runtime.h>
#include <hip/hip_bf16.h>
#include <stdint.h>

typedef float   f32x4  __attribute__((ext_vector_type(4)));
typedef __bf16  bf16x8 __attribute__((ext_vector_type(8)));
typedef unsigned short u16x4 __attribute__((ext_vector_type(4)));
typedef unsigned short u16x8 __attribute__((ext_vector_type(8)));

__device__ __forceinline__ uint16_t f2b(float x) {
  union { float f; uint32_t u; } c; c.f = x;
  uint32_t u = c.u;
  return (uint16_t)((u + 0x7FFFu + ((u >> 16) & 1u)) >> 16);
}

__device__ __forceinline__ f32x4 mfma32(bf16x8 a, bf16x8 b, f32x4 c) {
  return __builtin_amdgcn_mfma_f32_16x16x32_bf16(a, b, c, 0, 0, 0);
}

#define GLDS16(g, l) __builtin_amdgcn_global_load_lds( \
    (const __attribute__((address_space(1))) void*)(const void*)(g), \
    (__attribute__((address_space(3))) void*)(void*)(l), 16, 0, 0)

// ---------------- fp32 -> bf16 convert ----------------
__global__ __launch_bounds__(256) void f2b_k(const float* __restrict__ in,
                                             uint16_t* __restrict__ out, int n) {
  int i = (blockIdx.x * 256 + threadIdx.x) * 4;
  if (i >= n) return;
  f32x4 v = *(const f32x4*)(in + i);
  u16x4 o;
  o[0] = f2b(v[0]); o[1] = f2b(v[1]); o[2] = f2b(v[2]); o[3] = f2b(v[3]);
  *(u16x4*)(out + i) = o;
}

// ---------------- weight transpose: W (1024 x 1024, KxN) -> WT (NxK) bf16 ----------------
__global__ __launch_bounds__(256) void wtrans_k(const float* __restrict__ W,
                                                uint16_t* __restrict__ WT) {
  __shared__ float tl[32][33];
  const int n0 = blockIdx.x * 32, k0 = blockIdx.y * 32;
  const int tx = threadIdx.x, ty = threadIdx.y; // (32, 8)
#pragma unroll
  for (int i = 0; i < 32; i += 8)
    tl[ty + i][tx] = W[(size_t)(k0 + ty + i) * 1024 + n0 + tx];
  __syncthreads();
#pragma unroll
  for (int i = 0; i < 32; i += 8)
    WT[(size_t)(n0 + ty + i) * 1024 + k0 + tx] = f2b(tl[tx][ty + i]);
}

// ---------------- V transpose: qkv (2048x3072) v-slice -> vT[(b*16+h)*64+d][s] ----------------
__global__ __launch_bounds__(256) void vtrans_k(const uint16_t* __restrict__ qkv,
                                                uint16_t* __restrict__ vT) {
  int idx = blockIdx.x * 256 + threadIdx.x;   // 0 .. 2M-1
  int s  = idx & 1023;
  int r  = idx >> 10;
  int d  = r & 63;
  int bh = r >> 6;
  int b = bh >> 4, h = bh & 15;
  vT[idx] = qkv[(size_t)(b * 1024 + s) * 3072 + 2048 + h * 64 + d];
}

// ---------------- GEMM: C = A(bf16, M x 1024) * BT(bf16, N x 1024)^T + bias [+res/gelu] ----------------
enum { EPI_BF16 = 0, EPI_RES = 1, EPI_GELU = 2 };

template<int EPI>
__global__ __launch_bounds__(256) void gemm_k(
    const uint16_t* __restrict__ A, int lda,
    const uint16_t* __restrict__ BT,
    const float* __restrict__ bias,
    const float* __restrict__ res,
    void* __restrict__ Cv, int ldc) {
  __shared__ uint16_t As[128 * 32];
  __shared__ uint16_t Bs[128 * 32];
  const int t = threadIdx.x;
  const int lane = t & 63, w = t >> 6;
  const int wr = w >> 1, wc = w & 1;
  const int l15 = lane & 15, g = lane >> 4;
  const int bm0 = blockIdx.y * 128, bn0 = blockIdx.x * 128;

  const uint16_t* ga = A  + (size_t)(bm0 + (t >> 2)) * lda  + (t & 3) * 8;
  const uint16_t* gb = BT + (size_t)(bn0 + (t >> 2)) * 1024 + (t & 3) * 8;

  f32x4 acc[4][4] = {};

  for (int k0 = 0; k0 < 1024; k0 += 32) {
    __syncthreads();
    GLDS16(ga + k0,                     &As[t * 8]);
    GLDS16(ga + (size_t)64 * lda + k0,  &As[2048 + t * 8]);
    GLDS16(gb + k0,                     &Bs[t * 8]);
    GLDS16(gb + 64 * 1024 + k0,         &Bs[2048 + t * 8]);
    __syncthreads();
    bf16x8 af[4], bf[4];
#pragma unroll
    for (int i = 0; i < 4; i++)
      af[i] = *(const bf16x8*)&As[(wr * 64 + i * 16 + l15) * 32 + g * 8];
#pragma unroll
    for (int i = 0; i < 4; i++)
      bf[i] = *(const bf16x8*)&Bs[(wc * 64 + i * 16 + l15) * 32 + g * 8];
#pragma unroll
    for (int mi = 0; mi < 4; mi++)
#pragma unroll
      for (int ni = 0; ni < 4; ni++)
        acc[mi][ni] = mfma32(af[mi], bf[ni], acc[mi][ni]);
  }

#pragma unroll
  for (int mi = 0; mi < 4; mi++) {
#pragma unroll
    for (int ni = 0; ni < 4; ni++) {
      const int row0 = bm0 + wr * 64 + mi * 16 + g * 4;
      const int col  = bn0 + wc * 64 + ni * 16 + l15;
      const float bc = bias[col];
#pragma unroll
      for (int r = 0; r < 4; r++) {
        float v = acc[mi][ni][r] + bc;
        const size_t idx = (size_t)(row0 + r) * ldc + col;
        if constexpr (EPI == EPI_RES) {
          ((float*)Cv)[idx] = v + res[idx];
        } else if constexpr (EPI == EPI_GELU) {
          float gl = 0.5f * v * (1.0f + erff(v * 0.70710678118654752f));
          ((uint16_t*)Cv)[idx] = f2b(gl);
        } else {
          ((uint16_t*)Cv)[idx] = f2b(v);
        }
      }
    }
  }
}

// ---------------- fused 3-branch max-softmax attention (LDS-staged) ----------------
// grid (S/64, H, B), 256 threads = 4 waves; wave w owns q rows q0..q0+15.
// K tiles (64 rows x 64 d, 3 branches) and V^T tile (64 d x 64 s) are staged in
// LDS via global_load_lds in FRAGMENT-MAJOR order: every MFMA operand read is a
// linear ds_read_b128 at base + lane*16 (zero bank conflicts).
// K rows are PERMUTED at stage time so that the P-fragment contraction-slot map
// becomes slot(g*8+j) <-> s = kk*32 + g*8 + j, which makes the V fragment a
// single contiguous 16B read. Pass 1 (Z per branch) is order-independent, so it
// uses the same staging. P = exp2(max_b (s_b*scl2 - log2 Z_b)) -- one exp per
// element instead of three.
__global__ __launch_bounds__(256) void attn_k(
    const uint16_t* __restrict__ qkv,
    const uint16_t* __restrict__ sqk0,
    const uint16_t* __restrict__ sqk1,
    const uint16_t* __restrict__ vT,
    uint16_t* __restrict__ O) {
  __shared__ uint16_t Ks0[4096];
  __shared__ uint16_t Ks1[4096];
  __shared__ uint16_t Ks2[4096];
  __shared__ uint16_t Vs[4096];

  const int t = threadIdx.x;
  const int lane = t & 63, w = t >> 6;
  const int l15 = lane & 15, g = lane >> 4;
  const int h = blockIdx.y, b = blockIdx.z;
  const int q0 = blockIdx.x * 64 + w * 16;
  const float scl2 = 0.03125f * 1.44269504088896f;  // (1/sqrt(1024)) * log2(e)
  const size_t rq = (size_t)(b * 1024 + q0 + l15);

  // Q fragments (per-lane 16B gathers, once)
  bf16x8 qf[3][2];
  {
    const uint16_t* p = qkv + rq * 3072 + h * 64 + g * 8;
    qf[0][0] = *(const bf16x8*)p; qf[0][1] = *(const bf16x8*)(p + 32);
    p = sqk0 + rq * 2048 + h * 64 + g * 8;
    qf[1][0] = *(const bf16x8*)p; qf[1][1] = *(const bf16x8*)(p + 32);
    p = sqk1 + rq * 2048 + h * 64 + g * 8;
    qf[2][0] = *(const bf16x8*)p; qf[2][1] = *(const bf16x8*)(p + 32);
  }

  // --- staging source addresses (per thread) ---
  // thread t stages LDS bytes [t*16, t*16+16) of call c (c=0: subtiles 0,1; c=1: 2,3)
  // LDS fragment-major: [st][half][g][l15] ; K-row permutation:
  //   s_local(st=c*2+stq, p) = c*32 + (p>>2)*8 + stq*4 + (p&3)
  const int p_   = t & 15;
  const int gg_  = (t >> 4) & 3;
  const int hf_  = (t >> 6) & 1;
  const int stq_ = t >> 7;
  const int srow0   = ((p_ >> 2) << 3) + stq_ * 4 + (p_ & 3); // s_local for c=0
  const int kcolel  = hf_ * 32 + gg_ * 8;

  const uint16_t* pk0b = qkv  + (size_t)b * 1024 * 3072 + 1024 + h * 64
                       + (size_t)srow0 * 3072 + kcolel;
  const uint16_t* pk1b = sqk0 + (size_t)b * 1024 * 2048 + 1024 + h * 64
                       + (size_t)srow0 * 2048 + kcolel;
  const uint16_t* pk2b = sqk1 + (size_t)b * 1024 * 2048 + 1024 + h * 64
                       + (size_t)srow0 * 2048 + kcolel;
  // V staging: LDS [kk=c][dt][g][l15]; source row d = (t>>6)*16 + (t&15), s = c*32 + g*8
  const uint16_t* pvb = vT + ((size_t)(b * 16 + h) * 64 + (t >> 6) * 16 + (t & 15)) * 1024
                      + gg_ * 8;

  // ---- pass 1: Z per branch per q row ----
  float z0 = 0.f, z1 = 0.f, z2 = 0.f;
  {
    const uint16_t* pk0 = pk0b;
    const uint16_t* pk1 = pk1b;
    const uint16_t* pk2 = pk2b;
    for (int kt = 0; kt < 16; kt++) {
      __syncthreads();
      GLDS16(pk0,             &Ks0[t * 8]);
      GLDS16(pk0 + 32 * 3072, &Ks0[2048 + t * 8]);
      GLDS16(pk1,             &Ks1[t * 8]);
      GLDS16(pk1 + 32 * 2048, &Ks1[2048 + t * 8]);
      GLDS16(pk2,             &Ks2[t * 8]);
      GLDS16(pk2 + 32 * 2048, &Ks2[2048 + t * 8]);
      pk0 += 64 * 3072; pk1 += 64 * 2048; pk2 += 64 * 2048;
      __syncthreads();
#pragma unroll
      for (int st = 0; st < 4; st++) {
        f32x4 c0 = {}, c1 = {}, c2 = {};
        c0 = mfma32(*(const bf16x8*)&Ks0[st * 1024 + lane * 8],       qf[0][0], c0);
        c0 = mfma32(*(const bf16x8*)&Ks0[st * 1024 + 512 + lane * 8], qf[0][1], c0);
        c1 = mfma32(*(const bf16x8*)&Ks1[st * 1024 + lane * 8],       qf[1][0], c1);
        c1 = mfma32(*(const bf16x8*)&Ks1[st * 1024 + 512 + lane * 8], qf[1][1], c1);
        c2 = mfma32(*(const bf16x8*)&Ks2[st * 1024 + lane * 8],       qf[2][0], c2);
        c2 = mfma32(*(const bf16x8*)&Ks2[st * 1024 + 512 + lane * 8], qf[2][1], c2);
#pragma unroll
        for (int r = 0; r < 4; r++) {
          z0 += __builtin_amdgcn_exp2f(c0[r] * scl2);
          z1 += __builtin_amdgcn_exp2f(c1[r] * scl2);
          z2 += __builtin_amdgcn_exp2f(c2[r] * scl2);
        }
      }
    }
  }
  z0 += __shfl_xor(z0, 16, 64); z0 += __shfl_xor(z0, 32, 64);
  z1 += __shfl_xor(z1, 16, 64); z1 += __shfl_xor(z1, 32, 64);
  z2 += __shfl_xor(z2, 16, 64); z2 += __shfl_xor(z2, 32, 64);
  const float lz0 = __builtin_amdgcn_logf(z0);
  const float lz1 = __builtin_amdgcn_logf(z1);
  const float lz2 = __builtin_amdgcn_logf(z2);

  // ---- pass 2: P = exp2(max_b(s_b*scl2 - lz_b)), O^T += V^T * P^T ----
  f32x4 accO[4] = {};
  {
    const uint16_t* pk0 = pk0b;
    const uint16_t* pk1 = pk1b;
    const uint16_t* pk2 = pk2b;
    const uint16_t* pv  = pvb;
    for (int kt = 0; kt < 16; kt++) {
      __syncthreads();
      GLDS16(pk0,             &Ks0[t * 8]);
      GLDS16(pk0 + 32 * 3072, &Ks0[2048 + t * 8]);
      GLDS16(pk1,             &Ks1[t * 8]);
      GLDS16(pk1 + 32 * 2048, &Ks1[2048 + t * 8]);
      GLDS16(pk2,             &Ks2[t * 8]);
      GLDS16(pk2 + 32 * 2048, &Ks2[2048 + t * 8]);
      GLDS16(pv,              &Vs[t * 8]);
      GLDS16(pv + 32,         &Vs[2048 + t * 8]);
      pk0 += 64 * 3072; pk1 += 64 * 2048; pk2 += 64 * 2048; pv += 64;
      __syncthreads();
#pragma unroll
      for (int kk = 0; kk < 2; kk++) {
        u16x8 pu;
#pragma unroll
        for (int sub = 0; sub < 2; sub++) {
          const int st = kk * 2 + sub;
          f32x4 c0 = {}, c1 = {}, c2 = {};
          c0 = mfma32(*(const bf16x8*)&Ks0[st * 1024 + lane * 8],       qf[0][0], c0);
          c0 = mfma32(*(const bf16x8*)&Ks0[st * 1024 + 512 + lane * 8], qf[0][1], c0);
          c1 = mfma32(*(const bf16x8*)&Ks1[st * 1024 + lane * 8],       qf[1][0], c1);
          c1 = mfma32(*(const bf16x8*)&Ks1[st * 1024 + 512 + lane * 8], qf[1][1], c1);
          c2 = mfma32(*(const bf16x8*)&Ks2[st * 1024 + lane * 8],       qf[2][0], c2);
          c2 = mfma32(*(const bf16x8*)&Ks2[st * 1024 + 512 + lane * 8], qf[2][1], c2);
#pragma unroll
          for (int r = 0; r < 4; r++) {
            float m = fmaxf(fmaxf(c0[r] * scl2 - lz0, c1[r] * scl2 - lz1),
                            c2[r] * scl2 - lz2);
            pu[sub * 4 + r] = f2b(__builtin_amdgcn_exp2f(m));
          }
        }
        const bf16x8 pf = __builtin_bit_cast(bf16x8, pu);
#pragma unroll
        for (int dt = 0; dt < 4; dt++) {
          bf16x8 vf = *(const bf16x8*)&Vs[kk * 2048 + dt * 512 + lane * 8];
          accO[dt] = mfma32(vf, pf, accO[dt]);
        }
      }
    }
  }

  uint16_t* ob = O + rq * 1024 + h * 64;
#pragma unroll
  for (int dt = 0; dt < 4; dt++)
#pragma unroll
    for (int r = 0; r < 4; r++)
      ob[dt * 16 + g * 4 + r] = f2b(accO[dt][r]);
}

// ---------------- LayerNorm over rows of 1024 fp32, optional bf16 copy ----------------
template<int WB>
__global__ __launch_bounds__(256) void ln_k(const float* __restrict__ X,
                                            const float* __restrict__ G,
                                            const float* __restrict__ Bt,
                                            float* __restrict__ Yf,
                                            uint16_t* __restrict__ Yb) {
  const int row = blockIdx.x, t = threadIdx.x;
  const int lane = t & 63, w = t >> 6;
  const size_t base = (size_t)row * 1024 + t * 4;
  f32x4 x = *(const f32x4*)(X + base);
  float s  = x[0] + x[1] + x[2] + x[3];
  float s2 = x[0] * x[0] + x[1] * x[1] + x[2] * x[2] + x[3] * x[3];
#pragma unroll
  for (int o = 1; o < 64; o <<= 1) {
    s  += __shfl_xor(s,  o, 64);
    s2 += __shfl_xor(s2, o, 64);
  }
  __shared__ float red[8];
  if (lane == 0) { red[w] = s; red[4 + w] = s2; }
  __syncthreads();
  s  = red[0] + red[1] + red[2] + red[3];
  s2 = red[4] + red[5] + red[6] + red[7];
  const float mean = s * (1.0f / 1024.0f);
  const float rstd = rsqrtf(s2 * (1.0f / 1024.0f) - mean * mean + 1e-5f);
  f32x4 gv = *(const f32x4*)(G + t * 4);
  f32x4 bv = *(const f32x4*)(Bt + t * 4);
  f32x4 y;
#pragma unroll
  for (int i = 0; i < 4; i++) y[i] = (x[i] - mean) * rstd * gv[i] + bv[i];
  *(f32x4*)(Yf + base) = y;
  if constexpr (WB) {
    u16x4 o;
#pragma unroll
    for (int i = 0; i < 4; i++) o[i] = f2b(y[i]);
    *(u16x4*)(Yb + base) = o;
  }
}

// ---------------- host ----------------
extern "C" void kernel_launch(void* const* d_in, const int* in_sizes, int n_in,
                              void* d_out, int out_size, void* d_ws, size_t ws_size,
                              hipStream_t stream) {
  (void)in_sizes; (void)n_in; (void)out_size;
  const float* id_x = (const float*)d_in[0];
  const float* side = (const float*)d_in[1];
  const float* Wq  = (const float*)d_in[3];
  const float* bq  = (const float*)d_in[4];
  const float* Wk  = (const float*)d_in[5];
  const float* bk  = (const float*)d_in[6];
  const float* Wv  = (const float*)d_in[7];
  const float* bv  = (const float*)d_in[8];
  const float* sWq = (const float*)d_in[9];
  const float* sbq = (const float*)d_in[10];
  const float* sWk = (const float*)d_in[11];
  const float* sbk = (const float*)d_in[12];
  const float* Wo  = (const float*)d_in[13];
  const float* bo  = (const float*)d_in[14];
  const float* W1  = (const float*)d_in[15];
  const float* b1  = (const float*)d_in[16];
  const float* W2  = (const float*)d_in[17];
  const float* b2  = (const float*)d_in[18];
  const float* g1  = (const float*)d_in[19];
  const float* be1 = (const float*)d_in[20];
  const float* g2  = (const float*)d_in[21];
  const float* be2 = (const float*)d_in[22];

  char* ws = (char*)d_ws;
  const size_t oWT   = 0;                       // 10240x1024 bf16 = 20,971,520
  const size_t oBias = oWT + 20971520;          // 7168 f32 = 28,672
  const size_t oC    = oBias + 28672;           // 4 MB: xb, later Ob
  const size_t oD    = oC + 4194304;            // 8 MB: sdb
  const size_t oE    = oD + 8388608;            // 32 MB region
  const size_t total = oE + 33554432;           // 67,137,536
  if (ws_size < total) return;

  uint16_t* WT    = (uint16_t*)(ws + oWT);
  float*    biasc = (float*)(ws + oBias);
  uint16_t* xb    = (uint16_t*)(ws + oC);
  uint16_t* Ob    = (uint16_t*)(ws + oC);          // aliases xb (dead)
  uint16_t* sdb   = (uint16_t*)(ws + oD);
  char* E = ws + oE;
  uint16_t* qkv  = (uint16_t*)(E);                  // 12 MB
  uint16_t* sqk0 = (uint16_t*)(E + 12582912);       // 8 MB
  uint16_t* sqk1 = (uint16_t*)(E + 20971520);       // 8 MB
  uint16_t* vTp  = (uint16_t*)(E + 29360128);       // 4 MB
  // post-attention aliases (qkv/sqk/vT all dead after attn_k):
  float*    x1   = (float*)(E);                     // 8 MB
  float*    x1n  = (float*)(E + 8388608);           // 8 MB
  uint16_t* x1nb = (uint16_t*)(E + 16777216);       // 4 MB
  uint16_t* hb   = (uint16_t*)(E + 20971520 + 0);   // 4 MB (sqk1 region)
  float*    x2   = (float*)(E + 25165824);          // 8 MB

  // bias concat: [bq|bk|bv] , [sbq0|sbk0] , [sbq1|sbk1]
  hipMemcpyAsync(biasc + 0,    bq,        4096, hipMemcpyDeviceToDevice, stream);
  hipMemcpyAsync(biasc + 1024, bk,        4096, hipMemcpyDeviceToDevice, stream);
  hipMemcpyAsync(biasc + 2048, bv,        4096, hipMemcpyDeviceToDevice, stream);
  hipMemcpyAsync(biasc + 3072, sbq,       4096, hipMemcpyDeviceToDevice, stream);
  hipMemcpyAsync(biasc + 4096, sbk,       4096, hipMemcpyDeviceToDevice, stream);
  hipMemcpyAsync(biasc + 5120, sbq + 1024, 4096, hipMemcpyDeviceToDevice, stream);
  hipMemcpyAsync(biasc + 6144, sbk + 1024, 4096, hipMemcpyDeviceToDevice, stream);

  dim3 tb(32, 8), tg(32, 32);
  wtrans_k<<<tg, tb, 0, stream>>>(Wq,              WT + 0);
  wtrans_k<<<tg, tb, 0, stream>>>(Wk,              WT + 1048576);
  wtrans_k<<<tg, tb, 0, stream>>>(Wv,              WT + 2097152);
  wtrans_k<<<tg, tb, 0, stream>>>(sWq,             WT + 3145728);
  wtrans_k<<<tg, tb, 0, stream>>>(sWk,             WT + 4194304);
  wtrans_k<<<tg, tb, 0, stream>>>(sWq + 1048576,   WT + 5242880);
  wtrans_k<<<tg, tb, 0, stream>>>(sWk + 1048576,   WT + 6291456);
  wtrans_k<<<tg, tb, 0, stream>>>(Wo,              WT + 7340032);
  wtrans_k<<<tg, tb, 0, stream>>>(W1,              WT + 8388608);
  wtrans_k<<<tg, tb, 0, stream>>>(W2,              WT + 9437184);

  f2b_k<<<2048, 256, 0, stream>>>(id_x, xb, 2097152);
  f2b_k<<<4096, 256, 0, stream>>>(side, sdb, 4194304);

  gemm_k<EPI_BF16><<<dim3(24, 16), 256, 0, stream>>>(xb, 1024, WT,           biasc,        nullptr, qkv,  3072);
  gemm_k<EPI_BF16><<<dim3(16, 16), 256, 0, stream>>>(sdb, 2048, WT + 3145728, biasc + 3072, nullptr, sqk0, 2048);
  gemm_k<EPI_BF16><<<dim3(16, 16), 256, 0, stream>>>(sdb + 1024, 2048, WT + 5242880, biasc + 5120, nullptr, sqk1, 2048);

  vtrans_k<<<8192, 256, 0, stream>>>(qkv, vTp);
  attn_k<<<dim3(16, 16, 2), 256, 0, stream>>>(qkv, sqk0, sqk1, vTp, Ob);

  gemm_k<EPI_RES><<<dim3(8, 16), 256, 0, stream>>>(Ob, 1024, WT + 7340032, bo, id_x, x1, 1024);
  ln_k<1><<<2048, 256, 0, stream>>>(x1, g1, be1, x1n, x1nb);
  gemm_k<EPI_GELU><<<dim3(8, 16), 256, 0, stream>>>(x1nb, 1024, WT + 8388608, b1, nullptr, hb, 1024);
  gemm_k<EPI_RES><<<dim3(8, 16), 256, 0, stream>>>(hb, 1024, WT + 9437184, b2, x1n, x2, 1024);
  ln_k<0><<<2048, 256, 0, stream>>>(x2, g2, be2, (float*)d_out, nullptr);
}

// Round 3
// 261.602 us; speedup vs baseline: 1.7902x; 1.1359x over previous
//
#include <hip/hip_runtime.h>
#include <hip/hip_bf16.h>
#include <stdint.h>

typedef float   f32x4  __attribute__((ext_vector_type(4)));
typedef __bf16  bf16x8 __attribute__((ext_vector_type(8)));
typedef unsigned short u16x4 __attribute__((ext_vector_type(4)));
typedef unsigned short u16x8 __attribute__((ext_vector_type(8)));

__device__ __forceinline__ uint16_t f2b(float x) {
  union { float f; uint32_t u; } c; c.f = x;
  uint32_t u = c.u;
  return (uint16_t)((u + 0x7FFFu + ((u >> 16) & 1u)) >> 16);
}

__device__ __forceinline__ f32x4 mfma32(bf16x8 a, bf16x8 b, f32x4 c) {
  return __builtin_amdgcn_mfma_f32_16x16x32_bf16(a, b, c, 0, 0, 0);
}

#define GLDS16(g, l) __builtin_amdgcn_global_load_lds( \
    (const __attribute__((address_space(1))) void*)(const void*)(g), \
    (__attribute__((address_space(3))) void*)(void*)(l), 16, 0, 0)

#define WAITVM(N) asm volatile("s_waitcnt vmcnt(" #N ")" ::: "memory")
#define WAITLGKM0 asm volatile("s_waitcnt lgkmcnt(0)" ::: "memory")
#define BAR() __builtin_amdgcn_s_barrier()

// ---------------- fp32 -> bf16 convert ----------------
__global__ __launch_bounds__(256) void f2b_k(const float* __restrict__ in,
                                             uint16_t* __restrict__ out, int n) {
  int i = (blockIdx.x * 256 + threadIdx.x) * 4;
  if (i >= n) return;
  f32x4 v = *(const f32x4*)(in + i);
  u16x4 o;
  o[0] = f2b(v[0]); o[1] = f2b(v[1]); o[2] = f2b(v[2]); o[3] = f2b(v[3]);
  *(u16x4*)(out + i) = o;
}

// ---------------- bias concat: [bq|bk|bv|sbq0|sbk0|sbq1|sbk1] ----------------
__global__ __launch_bounds__(256) void biascat_k(
    const float* __restrict__ bq, const float* __restrict__ bk,
    const float* __restrict__ bv, const float* __restrict__ sbq,
    const float* __restrict__ sbk, float* __restrict__ out) {
  int i = blockIdx.x * 256 + threadIdx.x;  // 0..7167
  int seg = i >> 10, off = i & 1023;
  float v;
  switch (seg) {
    case 0: v = bq[off]; break;
    case 1: v = bk[off]; break;
    case 2: v = bv[off]; break;
    case 3: v = sbq[off]; break;
    case 4: v = sbk[off]; break;
    case 5: v = sbq[1024 + off]; break;
    default: v = sbk[1024 + off]; break;
  }
  out[i] = v;
}

// ---------------- all weight transposes in one launch: z selects the matrix ----------------
__global__ __launch_bounds__(256) void wtrans_all(
    const float* __restrict__ W0, const float* __restrict__ W1,
    const float* __restrict__ W2, const float* __restrict__ W3,
    const float* __restrict__ W4, const float* __restrict__ W5,
    const float* __restrict__ W6, const float* __restrict__ W7,
    const float* __restrict__ W8, const float* __restrict__ W9,
    uint16_t* __restrict__ WT) {
  const float* W;
  switch (blockIdx.z) {
    case 0: W = W0; break; case 1: W = W1; break; case 2: W = W2; break;
    case 3: W = W3; break; case 4: W = W4; break; case 5: W = W5; break;
    case 6: W = W6; break; case 7: W = W7; break; case 8: W = W8; break;
    default: W = W9; break;
  }
  uint16_t* dst = WT + (size_t)blockIdx.z * 1048576;
  __shared__ float tl[32][33];
  const int n0 = blockIdx.x * 32, k0 = blockIdx.y * 32;
  const int tx = threadIdx.x, ty = threadIdx.y; // (32, 8)
#pragma unroll
  for (int i = 0; i < 32; i += 8)
    tl[ty + i][tx] = W[(size_t)(k0 + ty + i) * 1024 + n0 + tx];
  __syncthreads();
#pragma unroll
  for (int i = 0; i < 32; i += 8)
    dst[(size_t)(n0 + ty + i) * 1024 + k0 + tx] = f2b(tl[tx][ty + i]);
}

// ---------------- V transpose (coalesced LDS tile) ----------------
__global__ __launch_bounds__(256) void vtrans_k(const uint16_t* __restrict__ qkv,
                                                uint16_t* __restrict__ vT) {
  __shared__ uint16_t tl[64][65];
  const int st = blockIdx.x, h = blockIdx.y, b = blockIdx.z;
  const int t = threadIdx.x;
  const int row = t >> 3, c8 = t & 7;
  const uint16_t* src = qkv + (size_t)(b * 1024 + st * 64) * 3072 + 2048 + h * 64;
#pragma unroll
  for (int it = 0; it < 2; it++) {
    int r = row + it * 32;
    u16x8 v = *(const u16x8*)(src + (size_t)r * 3072 + c8 * 8);
#pragma unroll
    for (int j = 0; j < 8; j++) tl[c8 * 8 + j][r] = v[j];
  }
  __syncthreads();
  const int d = t >> 2, s0 = (t & 3) * 16;
  uint16_t* dstp = vT + ((size_t)((b * 16 + h) * 64 + d)) * 1024 + st * 64 + s0;
  u16x8 o1, o2;
#pragma unroll
  for (int j = 0; j < 8; j++) { o1[j] = tl[d][s0 + j]; o2[j] = tl[d][s0 + 8 + j]; }
  *(u16x8*)dstp = o1;
  *(u16x8*)(dstp + 8) = o2;
}

// ---------------- GEMM 128x128 (pipelined 2-phase) ----------------
enum { EPI_BF16 = 0, EPI_RES = 1, EPI_GELU = 2 };

template<int EPI>
__global__ __launch_bounds__(256) void gemm_k(
    const uint16_t* __restrict__ A, int lda,
    const uint16_t* __restrict__ BT,
    const float* __restrict__ bias,
    const float* __restrict__ res,
    void* __restrict__ Cv, int ldc) {
  __shared__ uint16_t As[2][4096];
  __shared__ uint16_t Bs[2][4096];
  const int t = threadIdx.x;
  const int lane = t & 63, w = t >> 6;
  const int wr = w >> 1, wc = w & 1;
  const int l15 = lane & 15, g = lane >> 4;
  const int bm0 = blockIdx.y * 128, bn0 = blockIdx.x * 128;

  const uint16_t* ga = A  + (size_t)(bm0 + (t >> 2)) * lda  + (t & 3) * 8;
  const uint16_t* gb = BT + (size_t)(bn0 + (t >> 2)) * 1024 + (t & 3) * 8;

#define GSTAGE(bufi, k0) do { \
    GLDS16(ga + (k0),                    &As[bufi][t * 8]); \
    GLDS16(ga + (size_t)64 * lda + (k0), &As[bufi][2048 + t * 8]); \
    GLDS16(gb + (k0),                    &Bs[bufi][t * 8]); \
    GLDS16(gb + 64 * 1024 + (k0),        &Bs[bufi][2048 + t * 8]); } while (0)

  f32x4 acc[4][4] = {};
  int cur = 0;
  GSTAGE(0, 0);
  for (int it = 0; it < 32; it++) {
    if (it < 31) { GSTAGE(cur ^ 1, (it + 1) * 32); WAITVM(4); }
    else WAITVM(0);
    BAR();
    bf16x8 af[4], bf[4];
#pragma unroll
    for (int i = 0; i < 4; i++)
      af[i] = *(const bf16x8*)&As[cur][(wr * 64 + i * 16 + l15) * 32 + g * 8];
#pragma unroll
    for (int i = 0; i < 4; i++)
      bf[i] = *(const bf16x8*)&Bs[cur][(wc * 64 + i * 16 + l15) * 32 + g * 8];
#pragma unroll
    for (int mi = 0; mi < 4; mi++)
#pragma unroll
      for (int ni = 0; ni < 4; ni++)
        acc[mi][ni] = mfma32(af[mi], bf[ni], acc[mi][ni]);
    WAITLGKM0;
    BAR();
    cur ^= 1;
  }
#undef GSTAGE

#pragma unroll
  for (int mi = 0; mi < 4; mi++) {
#pragma unroll
    for (int ni = 0; ni < 4; ni++) {
      const int row0 = bm0 + wr * 64 + mi * 16 + g * 4;
      const int col  = bn0 + wc * 64 + ni * 16 + l15;
      const float bc = bias[col];
#pragma unroll
      for (int r = 0; r < 4; r++) {
        float v = acc[mi][ni][r] + bc;
        const size_t idx = (size_t)(row0 + r) * ldc + col;
        if constexpr (EPI == EPI_RES) {
          ((float*)Cv)[idx] = v + res[idx];
        } else if constexpr (EPI == EPI_GELU) {
          float gl = 0.5f * v * (1.0f + erff(v * 0.70710678118654752f));
          ((uint16_t*)Cv)[idx] = f2b(gl);
        } else {
          ((uint16_t*)Cv)[idx] = f2b(v);
        }
      }
    }
  }
}

// ---------------- GEMM 64x128 (pipelined; for M=2048,N=1024 tails -> 256 blocks) ----------------
template<int EPI>
__global__ __launch_bounds__(256) void gemm64_k(
    const uint16_t* __restrict__ A, int lda,
    const uint16_t* __restrict__ BT,
    const float* __restrict__ bias,
    const float* __restrict__ res,
    void* __restrict__ Cv, int ldc) {
  __shared__ uint16_t As[2][2048];
  __shared__ uint16_t Bs[2][4096];
  const int t = threadIdx.x;
  const int lane = t & 63, w = t >> 6;
  const int l15 = lane & 15, g = lane >> 4;
  const int bm0 = blockIdx.y * 64, bn0 = blockIdx.x * 128;

  const uint16_t* ga = A  + (size_t)(bm0 + (t >> 2)) * lda  + (t & 3) * 8;
  const uint16_t* gb = BT + (size_t)(bn0 + (t >> 2)) * 1024 + (t & 3) * 8;

#define GSTAGE64(bufi, k0) do { \
    GLDS16(ga + (k0),             &As[bufi][t * 8]); \
    GLDS16(gb + (k0),             &Bs[bufi][t * 8]); \
    GLDS16(gb + 64 * 1024 + (k0), &Bs[bufi][2048 + t * 8]); } while (0)

  f32x4 acc[4][2] = {};
  int cur = 0;
  GSTAGE64(0, 0);
  for (int it = 0; it < 32; it++) {
    if (it < 31) { GSTAGE64(cur ^ 1, (it + 1) * 32); WAITVM(3); }
    else WAITVM(0);
    BAR();
    bf16x8 af[4], bf[2];
#pragma unroll
    for (int i = 0; i < 4; i++)
      af[i] = *(const bf16x8*)&As[cur][(i * 16 + l15) * 32 + g * 8];
#pragma unroll
    for (int i = 0; i < 2; i++)
      bf[i] = *(const bf16x8*)&Bs[cur][(w * 32 + i * 16 + l15) * 32 + g * 8];
#pragma unroll
    for (int mi = 0; mi < 4; mi++)
#pragma unroll
      for (int ni = 0; ni < 2; ni++)
        acc[mi][ni] = mfma32(af[mi], bf[ni], acc[mi][ni]);
    WAITLGKM0;
    BAR();
    cur ^= 1;
  }
#undef GSTAGE64

#pragma unroll
  for (int mi = 0; mi < 4; mi++) {
#pragma unroll
    for (int ni = 0; ni < 2; ni++) {
      const int row0 = bm0 + mi * 16 + g * 4;
      const int col  = bn0 + w * 32 + ni * 16 + l15;
      const float bc = bias[col];
#pragma unroll
      for (int r = 0; r < 4; r++) {
        float v = acc[mi][ni][r] + bc;
        const size_t idx = (size_t)(row0 + r) * ldc + col;
        if constexpr (EPI == EPI_RES) {
          ((float*)Cv)[idx] = v + res[idx];
        } else if constexpr (EPI == EPI_GELU) {
          float gl = 0.5f * v * (1.0f + erff(v * 0.70710678118654752f));
          ((uint16_t*)Cv)[idx] = f2b(gl);
        } else {
          ((uint16_t*)Cv)[idx] = f2b(v);
        }
      }
    }
  }
}

// ---------------- fused 3-branch max-softmax attention ----------------
// 1D grid 512 blocks, XCD-bijective remap: all 16 q-tiles of one (h,b) land on
// one XCD (4 x 512KB K/V slices per XCD-L2). Double-buffered LDS staging with
// counted vmcnt (T3/T4): loads for tile t+1 stay in flight across the compute
// of tile t; vmcnt never drained to 0 in the steady-state loop.
__global__ __launch_bounds__(256) void attn_k(
    const uint16_t* __restrict__ qkv,
    const uint16_t* __restrict__ sqk0,
    const uint16_t* __restrict__ sqk1,
    const uint16_t* __restrict__ vT,
    uint16_t* __restrict__ O) {
  __shared__ uint16_t Ks0[2][4096];
  __shared__ uint16_t Ks1[2][4096];
  __shared__ uint16_t Ks2[2][4096];
  __shared__ uint16_t Vs[2][4096];

  const int t = threadIdx.x;
  const int lane = t & 63, w = t >> 6;
  const int l15 = lane & 15, g = lane >> 4;
  const int bid = blockIdx.x;
  const int xcd = bid & 7, idx = bid >> 3;
  const int hb = xcd * 4 + (idx >> 4);     // 0..31
  const int qt = idx & 15;
  const int b = hb >> 4, h = hb & 15;
  const int q0 = qt * 64 + w * 16;
  const float scl2 = 0.03125f * 1.44269504088896f;  // (1/sqrt(1024)) * log2(e)
  const size_t rq = (size_t)(b * 1024 + q0 + l15);

  // Q fragments (per-lane 16B gathers, once)
  bf16x8 qf[3][2];
  {
    const uint16_t* p = qkv + rq * 3072 + h * 64 + g * 8;
    qf[0][0] = *(const bf16x8*)p; qf[0][1] = *(const bf16x8*)(p + 32);
    p = sqk0 + rq * 2048 + h * 64 + g * 8;
    qf[1][0] = *(const bf16x8*)p; qf[1][1] = *(const bf16x8*)(p + 32);
    p = sqk1 + rq * 2048 + h * 64 + g * 8;
    qf[2][0] = *(const bf16x8*)p; qf[2][1] = *(const bf16x8*)(p + 32);
  }

  // staging source addresses (fragment-major K-row permutation; see round-2 notes)
  const int p_   = t & 15;
  const int gg_  = (t >> 4) & 3;
  const int hf_  = (t >> 6) & 1;
  const int stq_ = t >> 7;
  const int srow0  = ((p_ >> 2) << 3) + stq_ * 4 + (p_ & 3);
  const int kcolel = hf_ * 32 + gg_ * 8;

  const uint16_t* pk0b = qkv  + (size_t)b * 1024 * 3072 + 1024 + h * 64
                       + (size_t)srow0 * 3072 + kcolel;
  const uint16_t* pk1b = sqk0 + (size_t)b * 1024 * 2048 + 1024 + h * 64
                       + (size_t)srow0 * 2048 + kcolel;
  const uint16_t* pk2b = sqk1 + (size_t)b * 1024 * 2048 + 1024 + h * 64
                       + (size_t)srow0 * 2048 + kcolel;
  const uint16_t* pvb = vT + ((size_t)(b * 16 + h) * 64 + (t >> 6) * 16 + (t & 15)) * 1024
                      + gg_ * 8;

#define STAGE_K(bufi) do { \
    GLDS16(pk0,             &Ks0[bufi][t * 8]); \
    GLDS16(pk0 + 32 * 3072, &Ks0[bufi][2048 + t * 8]); \
    GLDS16(pk1,             &Ks1[bufi][t * 8]); \
    GLDS16(pk1 + 32 * 2048, &Ks1[bufi][2048 + t * 8]); \
    GLDS16(pk2,             &Ks2[bufi][t * 8]); \
    GLDS16(pk2 + 32 * 2048, &Ks2[bufi][2048 + t * 8]); \
    pk0 += 64 * 3072; pk1 += 64 * 2048; pk2 += 64 * 2048; } while (0)

#define STAGE_V(bufi) do { \
    GLDS16(pv,      &Vs[bufi][t * 8]); \
    GLDS16(pv + 32, &Vs[bufi][2048 + t * 8]); \
    pv += 64; } while (0)

  // ---- pass 1: Z per branch per q row ----
  float z0 = 0.f, z1 = 0.f, z2 = 0.f;
  {
    const uint16_t* pk0 = pk0b;
    const uint16_t* pk1 = pk1b;
    const uint16_t* pk2 = pk2b;
    int cur = 0;
    STAGE_K(0);
    for (int kt = 0; kt < 16; kt++) {
      if (kt < 15) { STAGE_K(cur ^ 1); WAITVM(6); }
      else WAITVM(0);
      BAR();
#pragma unroll
      for (int st = 0; st < 4; st++) {
        f32x4 c0 = {}, c1 = {}, c2 = {};
        c0 = mfma32(*(const bf16x8*)&Ks0[cur][st * 1024 + lane * 8],       qf[0][0], c0);
        c0 = mfma32(*(const bf16x8*)&Ks0[cur][st * 1024 + 512 + lane * 8], qf[0][1], c0);
        c1 = mfma32(*(const bf16x8*)&Ks1[cur][st * 1024 + lane * 8],       qf[1][0], c1);
        c1 = mfma32(*(const bf16x8*)&Ks1[cur][st * 1024 + 512 + lane * 8], qf[1][1], c1);
        c2 = mfma32(*(const bf16x8*)&Ks2[cur][st * 1024 + lane * 8],       qf[2][0], c2);
        c2 = mfma32(*(const bf16x8*)&Ks2[cur][st * 1024 + 512 + lane * 8], qf[2][1], c2);
#pragma unroll
        for (int r = 0; r < 4; r++) {
          z0 += __builtin_amdgcn_exp2f(c0[r] * scl2);
          z1 += __builtin_amdgcn_exp2f(c1[r] * scl2);
          z2 += __builtin_amdgcn_exp2f(c2[r] * scl2);
        }
      }
      WAITLGKM0;
      BAR();
      cur ^= 1;
    }
  }
  z0 += __shfl_xor(z0, 16, 64); z0 += __shfl_xor(z0, 32, 64);
  z1 += __shfl_xor(z1, 16, 64); z1 += __shfl_xor(z1, 32, 64);
  z2 += __shfl_xor(z2, 16, 64); z2 += __shfl_xor(z2, 32, 64);
  const float lz0 = __builtin_amdgcn_logf(z0);
  const float lz1 = __builtin_amdgcn_logf(z1);
  const float lz2 = __builtin_amdgcn_logf(z2);

  // ---- pass 2: P = exp2(max_b(s_b*scl2 - lz_b)), O^T += V^T * P^T ----
  f32x4 accO[4] = {};
  {
    const uint16_t* pk0 = pk0b;
    const uint16_t* pk1 = pk1b;
    const uint16_t* pk2 = pk2b;
    const uint16_t* pv  = pvb;
    int cur = 0;
    STAGE_K(0); STAGE_V(0);
    for (int kt = 0; kt < 16; kt++) {
      if (kt < 15) { STAGE_K(cur ^ 1); STAGE_V(cur ^ 1); WAITVM(8); }
      else WAITVM(0);
      BAR();
#pragma unroll
      for (int kk = 0; kk < 2; kk++) {
        u16x8 pu;
#pragma unroll
        for (int sub = 0; sub < 2; sub++) {
          const int st = kk * 2 + sub;
          f32x4 c0 = {}, c1 = {}, c2 = {};
          c0 = mfma32(*(const bf16x8*)&Ks0[cur][st * 1024 + lane * 8],       qf[0][0], c0);
          c0 = mfma32(*(const bf16x8*)&Ks0[cur][st * 1024 + 512 + lane * 8], qf[0][1], c0);
          c1 = mfma32(*(const bf16x8*)&Ks1[cur][st * 1024 + lane * 8],       qf[1][0], c1);
          c1 = mfma32(*(const bf16x8*)&Ks1[cur][st * 1024 + 512 + lane * 8], qf[1][1], c1);
          c2 = mfma32(*(const bf16x8*)&Ks2[cur][st * 1024 + lane * 8],       qf[2][0], c2);
          c2 = mfma32(*(const bf16x8*)&Ks2[cur][st * 1024 + 512 + lane * 8], qf[2][1], c2);
#pragma unroll
          for (int r = 0; r < 4; r++) {
            float m = fmaxf(fmaxf(c0[r] * scl2 - lz0, c1[r] * scl2 - lz1),
                            c2[r] * scl2 - lz2);
            pu[sub * 4 + r] = f2b(__builtin_amdgcn_exp2f(m));
          }
        }
        const bf16x8 pf = __builtin_bit_cast(bf16x8, pu);
#pragma unroll
        for (int dt = 0; dt < 4; dt++) {
          bf16x8 vf = *(const bf16x8*)&Vs[cur][kk * 2048 + dt * 512 + lane * 8];
          accO[dt] = mfma32(vf, pf, accO[dt]);
        }
      }
      WAITLGKM0;
      BAR();
      cur ^= 1;
    }
  }
#undef STAGE_K
#undef STAGE_V

  uint16_t* ob = O + rq * 1024 + h * 64;
#pragma unroll
  for (int dt = 0; dt < 4; dt++)
#pragma unroll
    for (int r = 0; r < 4; r++)
      ob[dt * 16 + g * 4 + r] = f2b(accO[dt][r]);
}

// ---------------- LayerNorm over rows of 1024 fp32, optional bf16 copy ----------------
template<int WB>
__global__ __launch_bounds__(256) void ln_k(const float* __restrict__ X,
                                            const float* __restrict__ G,
                                            const float* __restrict__ Bt,
                                            float* __restrict__ Yf,
                                            uint16_t* __restrict__ Yb) {
  const int row = blockIdx.x, t = threadIdx.x;
  const int lane = t & 63, w = t >> 6;
  const size_t base = (size_t)row * 1024 + t * 4;
  f32x4 x = *(const f32x4*)(X + base);
  float s  = x[0] + x[1] + x[2] + x[3];
  float s2 = x[0] * x[0] + x[1] * x[1] + x[2] * x[2] + x[3] * x[3];
#pragma unroll
  for (int o = 1; o < 64; o <<= 1) {
    s  += __shfl_xor(s,  o, 64);
    s2 += __shfl_xor(s2, o, 64);
  }
  __shared__ float red[8];
  if (lane == 0) { red[w] = s; red[4 + w] = s2; }
  __syncthreads();
  s  = red[0] + red[1] + red[2] + red[3];
  s2 = red[4] + red[5] + red[6] + red[7];
  const float mean = s * (1.0f / 1024.0f);
  const float rstd = rsqrtf(s2 * (1.0f / 1024.0f) - mean * mean + 1e-5f);
  f32x4 gv = *(const f32x4*)(G + t * 4);
  f32x4 bv = *(const f32x4*)(Bt + t * 4);
  f32x4 y;
#pragma unroll
  for (int i = 0; i < 4; i++) y[i] = (x[i] - mean) * rstd * gv[i] + bv[i];
  *(f32x4*)(Yf + base) = y;
  if constexpr (WB) {
    u16x4 o;
#pragma unroll
    for (int i = 0; i < 4; i++) o[i] = f2b(y[i]);
    *(u16x4*)(Yb + base) = o;
  }
}

// ---------------- host ----------------
extern "C" void kernel_launch(void* const* d_in, const int* in_sizes, int n_in,
                              void* d_out, int out_size, void* d_ws, size_t ws_size,
                              hipStream_t stream) {
  (void)in_sizes; (void)n_in; (void)out_size;
  const float* id_x = (const float*)d_in[0];
  const float* side = (const float*)d_in[1];
  const float* Wq  = (const float*)d_in[3];
  const float* bq  = (const float*)d_in[4];
  const float* Wk  = (const float*)d_in[5];
  const float* bk  = (const float*)d_in[6];
  const float* Wv  = (const float*)d_in[7];
  const float* bv  = (const float*)d_in[8];
  const float* sWq = (const float*)d_in[9];
  const float* sbq = (const float*)d_in[10];
  const float* sWk = (const float*)d_in[11];
  const float* sbk = (const float*)d_in[12];
  const float* Wo  = (const float*)d_in[13];
  const float* bo  = (const float*)d_in[14];
  const float* W1  = (const float*)d_in[15];
  const float* b1  = (const float*)d_in[16];
  const float* W2  = (const float*)d_in[17];
  const float* b2  = (const float*)d_in[18];
  const float* g1  = (const float*)d_in[19];
  const float* be1 = (const float*)d_in[20];
  const float* g2  = (const float*)d_in[21];
  const float* be2 = (const float*)d_in[22];

  char* ws = (char*)d_ws;
  const size_t oWT   = 0;                       // 10240x1024 bf16 = 20,971,520
  const size_t oBias = oWT + 20971520;          // 7168 f32 = 28,672
  const size_t oC    = oBias + 28672;           // 4 MB: xb, later Ob
  const size_t oD    = oC + 4194304;            // 8 MB: sdb
  const size_t oE    = oD + 8388608;            // 32 MB region
  const size_t total = oE + 33554432;           // 67,137,536
  if (ws_size < total) return;

  uint16_t* WT    = (uint16_t*)(ws + oWT);
  float*    biasc = (float*)(ws + oBias);
  uint16_t* xb    = (uint16_t*)(ws + oC);
  uint16_t* Ob    = (uint16_t*)(ws + oC);          // aliases xb (dead)
  uint16_t* sdb   = (uint16_t*)(ws + oD);
  char* E = ws + oE;
  uint16_t* qkv  = (uint16_t*)(E);                  // 12 MB
  uint16_t* sqk0 = (uint16_t*)(E + 12582912);       // 8 MB
  uint16_t* sqk1 = (uint16_t*)(E + 20971520);       // 8 MB
  uint16_t* vTp  = (uint16_t*)(E + 29360128);       // 4 MB
  // post-attention aliases (qkv/sqk/vT all dead after attn_k):
  float*    x1   = (float*)(E);                     // 8 MB
  float*    x1n  = (float*)(E + 8388608);           // 8 MB
  uint16_t* x1nb = (uint16_t*)(E + 16777216);       // 4 MB
  uint16_t* hb   = (uint16_t*)(E + 20971520);       // 4 MB (sqk1 region)
  float*    x2   = (float*)(E + 25165824);          // 8 MB

  biascat_k<<<28, 256, 0, stream>>>(bq, bk, bv, sbq, sbk, biasc);
  wtrans_all<<<dim3(32, 32, 10), dim3(32, 8), 0, stream>>>(
      Wq, Wk, Wv, sWq, sWk, sWq + 1048576, sWk + 1048576, Wo, W1, W2, WT);

  f2b_k<<<2048, 256, 0, stream>>>(id_x, xb, 2097152);
  f2b_k<<<4096, 256, 0, stream>>>(side, sdb, 4194304);

  gemm_k<EPI_BF16><<<dim3(24, 16), 256, 0, stream>>>(xb, 1024, WT,            biasc,        nullptr, qkv,  3072);
  gemm_k<EPI_BF16><<<dim3(16, 16), 256, 0, stream>>>(sdb, 2048, WT + 3145728, biasc + 3072, nullptr, sqk0, 2048);
  gemm_k<EPI_BF16><<<dim3(16, 16), 256, 0, stream>>>(sdb + 1024, 2048, WT + 5242880, biasc + 5120, nullptr, sqk1, 2048);

  vtrans_k<<<dim3(16, 16, 2), 256, 0, stream>>>(qkv, vTp);
  attn_k<<<512, 256, 0, stream>>>(qkv, sqk0, sqk1, vTp, Ob);

  gemm64_k<EPI_RES><<<dim3(8, 32), 256, 0, stream>>>(Ob, 1024, WT + 7340032, bo, id_x, x1, 1024);
  ln_k<1><<<2048, 256, 0, stream>>>(x1, g1, be1, x1n, x1nb);
  gemm64_k<EPI_GELU><<<dim3(8, 32), 256, 0, stream>>>(x1nb, 1024, WT + 8388608, b1, nullptr, hb, 1024);
  gemm64_k<EPI_RES><<<dim3(8, 32), 256, 0, stream>>>(hb, 1024, WT + 9437184, b2, x1n, x2, 1024);
  ln_k<0><<<2048, 256, 0, stream>>>(x2, g2, be2, (float*)d_out, nullptr);
}

// Round 4
// 245.319 us; speedup vs baseline: 1.9090x; 1.0664x over previous
//
#include <hip/hip_runtime.h>
#include <hip/hip_bf16.h>
#include <stdint.h>

typedef float   f32x4  __attribute__((ext_vector_type(4)));
typedef __bf16  bf16x8 __attribute__((ext_vector_type(8)));
typedef unsigned short u16x4 __attribute__((ext_vector_type(4)));
typedef unsigned short u16x8 __attribute__((ext_vector_type(8)));

__device__ __forceinline__ uint16_t f2b(float x) {
  union { float f; uint32_t u; } c; c.f = x;
  uint32_t u = c.u;
  return (uint16_t)((u + 0x7FFFu + ((u >> 16) & 1u)) >> 16);
}
__device__ __forceinline__ float b2f(uint16_t x) {
  union { uint32_t u; float f; } c; c.u = ((uint32_t)x) << 16;
  return c.f;
}

__device__ __forceinline__ f32x4 mfma32(bf16x8 a, bf16x8 b, f32x4 c) {
  return __builtin_amdgcn_mfma_f32_16x16x32_bf16(a, b, c, 0, 0, 0);
}

#define GLDS16(g, l) __builtin_amdgcn_global_load_lds( \
    (const __attribute__((address_space(1))) void*)(const void*)(g), \
    (__attribute__((address_space(3))) void*)(void*)(l), 16, 0, 0)

#define WAITVM(N) asm volatile("s_waitcnt vmcnt(" #N ")" ::: "memory")
#define WAITLGKM0 asm volatile("s_waitcnt lgkmcnt(0)" ::: "memory")
#define BAR() __builtin_amdgcn_s_barrier()

// ---------------- fp32 -> bf16 convert ----------------
__global__ __launch_bounds__(256) void f2b_k(const float* __restrict__ in,
                                             uint16_t* __restrict__ out, int n) {
  int i = (blockIdx.x * 256 + threadIdx.x) * 4;
  if (i >= n) return;
  f32x4 v = *(const f32x4*)(in + i);
  u16x4 o;
  o[0] = f2b(v[0]); o[1] = f2b(v[1]); o[2] = f2b(v[2]); o[3] = f2b(v[3]);
  *(u16x4*)(out + i) = o;
}

// ---------------- bias concat: [bq|bk|bv|sbq0|sbk0|sbq1|sbk1] ----------------
__global__ __launch_bounds__(256) void biascat_k(
    const float* __restrict__ bq, const float* __restrict__ bk,
    const float* __restrict__ bv, const float* __restrict__ sbq,
    const float* __restrict__ sbk, float* __restrict__ out) {
  int i = blockIdx.x * 256 + threadIdx.x;  // 0..7167
  int seg = i >> 10, off = i & 1023;
  float v;
  switch (seg) {
    case 0: v = bq[off]; break;
    case 1: v = bk[off]; break;
    case 2: v = bv[off]; break;
    case 3: v = sbq[off]; break;
    case 4: v = sbk[off]; break;
    case 5: v = sbq[1024 + off]; break;
    default: v = sbk[1024 + off]; break;
  }
  out[i] = v;
}

// ---------------- all weight transposes in one launch ----------------
__global__ __launch_bounds__(256) void wtrans_all(
    const float* __restrict__ W0, const float* __restrict__ W1,
    const float* __restrict__ W2, const float* __restrict__ W3,
    const float* __restrict__ W4, const float* __restrict__ W5,
    const float* __restrict__ W6, const float* __restrict__ W7,
    const float* __restrict__ W8, const float* __restrict__ W9,
    uint16_t* __restrict__ WT) {
  const float* W;
  switch (blockIdx.z) {
    case 0: W = W0; break; case 1: W = W1; break; case 2: W = W2; break;
    case 3: W = W3; break; case 4: W = W4; break; case 5: W = W5; break;
    case 6: W = W6; break; case 7: W = W7; break; case 8: W = W8; break;
    default: W = W9; break;
  }
  uint16_t* dst = WT + (size_t)blockIdx.z * 1048576;
  __shared__ float tl[32][33];
  const int n0 = blockIdx.x * 32, k0 = blockIdx.y * 32;
  const int tx = threadIdx.x, ty = threadIdx.y; // (32, 8)
#pragma unroll
  for (int i = 0; i < 32; i += 8)
    tl[ty + i][tx] = W[(size_t)(k0 + ty + i) * 1024 + n0 + tx];
  __syncthreads();
#pragma unroll
  for (int i = 0; i < 32; i += 8)
    dst[(size_t)(n0 + ty + i) * 1024 + k0 + tx] = f2b(tl[tx][ty + i]);
}

// ---------------- merged projection GEMM (qkv + side0 + side1), 896 blocks ----
// qkv case also writes the transposed V copy from its epilogue (cols>=2048).
__global__ __launch_bounds__(256) void proj_k(
    const uint16_t* __restrict__ xb, const uint16_t* __restrict__ sdb,
    const uint16_t* __restrict__ WT, const float* __restrict__ biasc,
    uint16_t* __restrict__ qkv, uint16_t* __restrict__ sqk0,
    uint16_t* __restrict__ sqk1, uint16_t* __restrict__ vT) {
  __shared__ uint16_t As[2][4096];
  __shared__ uint16_t Bs[2][4096];
  const int bid = blockIdx.x;
  const uint16_t* A; const uint16_t* BT; const float* bias; uint16_t* C;
  int lda, ldc, bx, by;
  bool dovt = false;
  if (bid < 384) {
    bx = bid % 24; by = bid / 24;
    A = xb; lda = 1024; BT = WT; bias = biasc; C = qkv; ldc = 3072;
    dovt = bx >= 16;
  } else if (bid < 640) {
    int r = bid - 384; bx = r & 15; by = r >> 4;
    A = sdb; lda = 2048; BT = WT + 3145728; bias = biasc + 3072;
    C = sqk0; ldc = 2048;
  } else {
    int r = bid - 640; bx = r & 15; by = r >> 4;
    A = sdb + 1024; lda = 2048; BT = WT + 5242880; bias = biasc + 5120;
    C = sqk1; ldc = 2048;
  }
  const int t = threadIdx.x;
  const int lane = t & 63, w = t >> 6;
  const int wr = w >> 1, wc = w & 1;
  const int l15 = lane & 15, g = lane >> 4;
  const int bm0 = by * 128, bn0 = bx * 128;

  const uint16_t* ga = A  + (size_t)(bm0 + (t >> 2)) * lda  + (t & 3) * 8;
  const uint16_t* gb = BT + (size_t)(bn0 + (t >> 2)) * 1024 + (t & 3) * 8;

#define GSTAGE(bufi, k0) do { \
    GLDS16(ga + (k0),                    &As[bufi][t * 8]); \
    GLDS16(ga + (size_t)64 * lda + (k0), &As[bufi][2048 + t * 8]); \
    GLDS16(gb + (k0),                    &Bs[bufi][t * 8]); \
    GLDS16(gb + 64 * 1024 + (k0),        &Bs[bufi][2048 + t * 8]); } while (0)

  f32x4 acc[4][4] = {};
  int cur = 0;
  GSTAGE(0, 0);
  for (int it = 0; it < 32; it++) {
    if (it < 31) { GSTAGE(cur ^ 1, (it + 1) * 32); WAITVM(4); }
    else WAITVM(0);
    BAR();
    bf16x8 af[4], bf[4];
#pragma unroll
    for (int i = 0; i < 4; i++)
      af[i] = *(const bf16x8*)&As[cur][(wr * 64 + i * 16 + l15) * 32 + g * 8];
#pragma unroll
    for (int i = 0; i < 4; i++)
      bf[i] = *(const bf16x8*)&Bs[cur][(wc * 64 + i * 16 + l15) * 32 + g * 8];
#pragma unroll
    for (int mi = 0; mi < 4; mi++)
#pragma unroll
      for (int ni = 0; ni < 4; ni++)
        acc[mi][ni] = mfma32(af[mi], bf[ni], acc[mi][ni]);
    WAITLGKM0;
    BAR();
    cur ^= 1;
  }
#undef GSTAGE

#pragma unroll
  for (int mi = 0; mi < 4; mi++) {
#pragma unroll
    for (int ni = 0; ni < 4; ni++) {
      const int row0 = bm0 + wr * 64 + mi * 16 + g * 4;
      const int col  = bn0 + wc * 64 + ni * 16 + l15;
      const float bc = bias[col];
      u16x4 ov;
#pragma unroll
      for (int r = 0; r < 4; r++) {
        float v = acc[mi][ni][r] + bc;
        ov[r] = f2b(v);
        C[(size_t)(row0 + r) * ldc + col] = ov[r];
      }
      if (dovt) {
        const int cc = col - 2048, hh = cc >> 6, dd = cc & 63;
        const int bb = row0 >> 10, s0 = row0 & 1023;
        *(u16x4*)&vT[((size_t)((bb * 16 + hh) * 64 + dd)) * 1024 + s0] = ov;
      }
    }
  }
}

// ---------------- GEMM 64x128 (pipelined; tail GEMMs, 256 blocks) ----------------
enum { EPI_BF16 = 0, EPI_RES = 1, EPI_GELU = 2 };

template<int EPI>
__global__ __launch_bounds__(256) void gemm64_k(
    const uint16_t* __restrict__ A, int lda,
    const uint16_t* __restrict__ BT,
    const float* __restrict__ bias,
    const float* __restrict__ res,
    void* __restrict__ Cv, int ldc) {
  __shared__ uint16_t As[2][2048];
  __shared__ uint16_t Bs[2][4096];
  const int t = threadIdx.x;
  const int lane = t & 63, w = t >> 6;
  const int l15 = lane & 15, g = lane >> 4;
  const int bm0 = blockIdx.y * 64, bn0 = blockIdx.x * 128;

  const uint16_t* ga = A  + (size_t)(bm0 + (t >> 2)) * lda  + (t & 3) * 8;
  const uint16_t* gb = BT + (size_t)(bn0 + (t >> 2)) * 1024 + (t & 3) * 8;

#define GSTAGE64(bufi, k0) do { \
    GLDS16(ga + (k0),             &As[bufi][t * 8]); \
    GLDS16(gb + (k0),             &Bs[bufi][t * 8]); \
    GLDS16(gb + 64 * 1024 + (k0), &Bs[bufi][2048 + t * 8]); } while (0)

  f32x4 acc[4][2] = {};
  int cur = 0;
  GSTAGE64(0, 0);
  for (int it = 0; it < 32; it++) {
    if (it < 31) { GSTAGE64(cur ^ 1, (it + 1) * 32); WAITVM(3); }
    else WAITVM(0);
    BAR();
    bf16x8 af[4], bf[2];
#pragma unroll
    for (int i = 0; i < 4; i++)
      af[i] = *(const bf16x8*)&As[cur][(i * 16 + l15) * 32 + g * 8];
#pragma unroll
    for (int i = 0; i < 2; i++)
      bf[i] = *(const bf16x8*)&Bs[cur][(w * 32 + i * 16 + l15) * 32 + g * 8];
#pragma unroll
    for (int mi = 0; mi < 4; mi++)
#pragma unroll
      for (int ni = 0; ni < 2; ni++)
        acc[mi][ni] = mfma32(af[mi], bf[ni], acc[mi][ni]);
    WAITLGKM0;
    BAR();
    cur ^= 1;
  }
#undef GSTAGE64

#pragma unroll
  for (int mi = 0; mi < 4; mi++) {
#pragma unroll
    for (int ni = 0; ni < 2; ni++) {
      const int row0 = bm0 + mi * 16 + g * 4;
      const int col  = bn0 + w * 32 + ni * 16 + l15;
      const float bc = bias[col];
#pragma unroll
      for (int r = 0; r < 4; r++) {
        float v = acc[mi][ni][r] + bc;
        const size_t idx = (size_t)(row0 + r) * ldc + col;
        if constexpr (EPI == EPI_RES) {
          ((float*)Cv)[idx] = v + res[idx];
        } else if constexpr (EPI == EPI_GELU) {
          float gl = 0.5f * v * (1.0f + erff(v * 0.70710678118654752f));
          ((uint16_t*)Cv)[idx] = f2b(gl);
        } else {
          ((uint16_t*)Cv)[idx] = f2b(v);
        }
      }
    }
  }
}

// ---------------- attention pass 1: per-branch Z partials (k-split) ----------------
// grid 1024: bid -> xcd(0..7), grp = xcd*8 + (idx>>4) -> (hb, kc), qt = idx&15.
// Each block: 64 q rows x 512 k rows (kc half), KT=32 double-buffered tiles.
__global__ __launch_bounds__(256) void attn_z(
    const uint16_t* __restrict__ qkv,
    const uint16_t* __restrict__ sqk0,
    const uint16_t* __restrict__ sqk1,
    float* __restrict__ zp) {
  __shared__ uint16_t Ks0[2][2048];
  __shared__ uint16_t Ks1[2][2048];
  __shared__ uint16_t Ks2[2][2048];
  const int t = threadIdx.x;
  const int lane = t & 63, w = t >> 6;
  const int l15 = lane & 15, g = lane >> 4;
  const int bid = blockIdx.x;
  const int xcd = bid & 7, idx = bid >> 3;
  const int grp = xcd * 8 + (idx >> 4);
  const int qt = idx & 15;
  const int hb = grp >> 1, kc = grp & 1;
  const int b = hb >> 4, h = hb & 15;
  const int q0 = qt * 64 + w * 16;
  const float scl2 = 0.03125f * 1.44269504088896f;
  const size_t rq = (size_t)(b * 1024 + q0 + l15);

  bf16x8 qf[3][2];
  {
    const uint16_t* p = qkv + rq * 3072 + h * 64 + g * 8;
    qf[0][0] = *(const bf16x8*)p; qf[0][1] = *(const bf16x8*)(p + 32);
    p = sqk0 + rq * 2048 + h * 64 + g * 8;
    qf[1][0] = *(const bf16x8*)p; qf[1][1] = *(const bf16x8*)(p + 32);
    p = sqk1 + rq * 2048 + h * 64 + g * 8;
    qf[2][0] = *(const bf16x8*)p; qf[2][1] = *(const bf16x8*)(p + 32);
  }

  const int p_   = t & 15;
  const int gg_  = (t >> 4) & 3;
  const int hf_  = (t >> 6) & 1;
  const int stq_ = t >> 7;
  const int srow   = (p_ >> 2) * 8 + stq_ * 4 + (p_ & 3) + kc * 512;
  const int kcolel = hf_ * 32 + gg_ * 8;

  const uint16_t* pk0 = qkv  + (size_t)b * 1024 * 3072 + 1024 + h * 64
                      + (size_t)srow * 3072 + kcolel;
  const uint16_t* pk1 = sqk0 + (size_t)b * 1024 * 2048 + 1024 + h * 64
                      + (size_t)srow * 2048 + kcolel;
  const uint16_t* pk2 = sqk1 + (size_t)b * 1024 * 2048 + 1024 + h * 64
                      + (size_t)srow * 2048 + kcolel;

#define STAGE3(bufi) do { \
    GLDS16(pk0, &Ks0[bufi][t * 8]); \
    GLDS16(pk1, &Ks1[bufi][t * 8]); \
    GLDS16(pk2, &Ks2[bufi][t * 8]); \
    pk0 += 32 * 3072; pk1 += 32 * 2048; pk2 += 32 * 2048; } while (0)

  float z0 = 0.f, z1 = 0.f, z2 = 0.f;
  int cur = 0;
  STAGE3(0);
  for (int kt = 0; kt < 16; kt++) {
    if (kt < 15) { STAGE3(cur ^ 1); WAITVM(3); }
    else WAITVM(0);
    BAR();
#pragma unroll
    for (int st = 0; st < 2; st++) {
      f32x4 c0 = {}, c1 = {}, c2 = {};
      c0 = mfma32(*(const bf16x8*)&Ks0[cur][st * 1024 + lane * 8],       qf[0][0], c0);
      c0 = mfma32(*(const bf16x8*)&Ks0[cur][st * 1024 + 512 + lane * 8], qf[0][1], c0);
      c1 = mfma32(*(const bf16x8*)&Ks1[cur][st * 1024 + lane * 8],       qf[1][0], c1);
      c1 = mfma32(*(const bf16x8*)&Ks1[cur][st * 1024 + 512 + lane * 8], qf[1][1], c1);
      c2 = mfma32(*(const bf16x8*)&Ks2[cur][st * 1024 + lane * 8],       qf[2][0], c2);
      c2 = mfma32(*(const bf16x8*)&Ks2[cur][st * 1024 + 512 + lane * 8], qf[2][1], c2);
#pragma unroll
      for (int r = 0; r < 4; r++) {
        z0 += __builtin_amdgcn_exp2f(c0[r] * scl2);
        z1 += __builtin_amdgcn_exp2f(c1[r] * scl2);
        z2 += __builtin_amdgcn_exp2f(c2[r] * scl2);
      }
    }
    WAITLGKM0;
    BAR();
    cur ^= 1;
  }
#undef STAGE3
  z0 += __shfl_xor(z0, 16, 64); z0 += __shfl_xor(z0, 32, 64);
  z1 += __shfl_xor(z1, 16, 64); z1 += __shfl_xor(z1, 32, 64);
  z2 += __shfl_xor(z2, 16, 64); z2 += __shfl_xor(z2, 32, 64);
  if (lane < 16) {
    const int qi = hb * 1024 + q0 + l15;
    zp[kc * 32768 + qi]          = z0;
    zp[65536 + kc * 32768 + qi]  = z1;
    zp[131072 + kc * 32768 + qi] = z2;
  }
}

// ---------------- z reduce: lz_b = log2(z_b[kc0] + z_b[kc1]) ----------------
__global__ __launch_bounds__(256) void zred_k(const float* __restrict__ zp,
                                              float* __restrict__ lz) {
  int i = blockIdx.x * 256 + threadIdx.x;  // 0..98303
  int br = i >> 15, rem = i & 32767;
  lz[i] = __builtin_amdgcn_logf(zp[br * 65536 + rem] + zp[br * 65536 + 32768 + rem]);
}

// ---------------- attention pass 2: P = exp2(max_b(s*scl2 - lz_b)), partial O ----
__global__ __launch_bounds__(256) void attn_o(
    const uint16_t* __restrict__ qkv,
    const uint16_t* __restrict__ sqk0,
    const uint16_t* __restrict__ sqk1,
    const uint16_t* __restrict__ vT,
    const float* __restrict__ lz,
    uint16_t* __restrict__ op) {
  __shared__ uint16_t Ks0[2][2048];
  __shared__ uint16_t Ks1[2][2048];
  __shared__ uint16_t Ks2[2][2048];
  __shared__ uint16_t Vs[2][2048];
  const int t = threadIdx.x;
  const int lane = t & 63, w = t >> 6;
  const int l15 = lane & 15, g = lane >> 4;
  const int bid = blockIdx.x;
  const int xcd = bid & 7, idx = bid >> 3;
  const int grp = xcd * 8 + (idx >> 4);
  const int qt = idx & 15;
  const int hb = grp >> 1, kc = grp & 1;
  const int b = hb >> 4, h = hb & 15;
  const int q0 = qt * 64 + w * 16;
  const float scl2 = 0.03125f * 1.44269504088896f;
  const size_t rq = (size_t)(b * 1024 + q0 + l15);

  bf16x8 qf[3][2];
  {
    const uint16_t* p = qkv + rq * 3072 + h * 64 + g * 8;
    qf[0][0] = *(const bf16x8*)p; qf[0][1] = *(const bf16x8*)(p + 32);
    p = sqk0 + rq * 2048 + h * 64 + g * 8;
    qf[1][0] = *(const bf16x8*)p; qf[1][1] = *(const bf16x8*)(p + 32);
    p = sqk1 + rq * 2048 + h * 64 + g * 8;
    qf[2][0] = *(const bf16x8*)p; qf[2][1] = *(const bf16x8*)(p + 32);
  }
  const int lzq = hb * 1024 + q0 + l15;
  const float lz0 = lz[lzq], lz1 = lz[32768 + lzq], lz2 = lz[65536 + lzq];

  const int p_   = t & 15;
  const int gg_  = (t >> 4) & 3;
  const int hf_  = (t >> 6) & 1;
  const int stq_ = t >> 7;
  const int srow   = (p_ >> 2) * 8 + stq_ * 4 + (p_ & 3) + kc * 512;
  const int kcolel = hf_ * 32 + gg_ * 8;

  const uint16_t* pk0 = qkv  + (size_t)b * 1024 * 3072 + 1024 + h * 64
                      + (size_t)srow * 3072 + kcolel;
  const uint16_t* pk1 = sqk0 + (size_t)b * 1024 * 2048 + 1024 + h * 64
                      + (size_t)srow * 2048 + kcolel;
  const uint16_t* pk2 = sqk1 + (size_t)b * 1024 * 2048 + 1024 + h * 64
                      + (size_t)srow * 2048 + kcolel;
  const uint16_t* pv  = vT + ((size_t)hb * 64 + (t >> 6) * 16 + p_) * 1024
                      + kc * 512 + gg_ * 8;

#define STAGE4(bufi) do { \
    GLDS16(pk0, &Ks0[bufi][t * 8]); \
    GLDS16(pk1, &Ks1[bufi][t * 8]); \
    GLDS16(pk2, &Ks2[bufi][t * 8]); \
    GLDS16(pv,  &Vs[bufi][t * 8]); \
    pk0 += 32 * 3072; pk1 += 32 * 2048; pk2 += 32 * 2048; pv += 32; } while (0)

  f32x4 accO[4] = {};
  int cur = 0;
  STAGE4(0);
  for (int kt = 0; kt < 16; kt++) {
    if (kt < 15) { STAGE4(cur ^ 1); WAITVM(4); }
    else WAITVM(0);
    BAR();
    u16x8 pu;
#pragma unroll
    for (int sub = 0; sub < 2; sub++) {
      f32x4 c0 = {}, c1 = {}, c2 = {};
      c0 = mfma32(*(const bf16x8*)&Ks0[cur][sub * 1024 + lane * 8],       qf[0][0], c0);
      c0 = mfma32(*(const bf16x8*)&Ks0[cur][sub * 1024 + 512 + lane * 8], qf[0][1], c0);
      c1 = mfma32(*(const bf16x8*)&Ks1[cur][sub * 1024 + lane * 8],       qf[1][0], c1);
      c1 = mfma32(*(const bf16x8*)&Ks1[cur][sub * 1024 + 512 + lane * 8], qf[1][1], c1);
      c2 = mfma32(*(const bf16x8*)&Ks2[cur][sub * 1024 + lane * 8],       qf[2][0], c2);
      c2 = mfma32(*(const bf16x8*)&Ks2[cur][sub * 1024 + 512 + lane * 8], qf[2][1], c2);
#pragma unroll
      for (int r = 0; r < 4; r++) {
        float m = fmaxf(fmaxf(c0[r] * scl2 - lz0, c1[r] * scl2 - lz1),
                        c2[r] * scl2 - lz2);
        pu[sub * 4 + r] = f2b(__builtin_amdgcn_exp2f(m));
      }
    }
    const bf16x8 pf = __builtin_bit_cast(bf16x8, pu);
#pragma unroll
    for (int dt = 0; dt < 4; dt++) {
      bf16x8 vf = *(const bf16x8*)&Vs[cur][dt * 512 + lane * 8];
      accO[dt] = mfma32(vf, pf, accO[dt]);
    }
    WAITLGKM0;
    BAR();
    cur ^= 1;
  }
#undef STAGE4

  uint16_t* ob = op + (size_t)kc * 2097152 + rq * 1024 + h * 64;
#pragma unroll
  for (int dt = 0; dt < 4; dt++) {
    u16x4 o4;
#pragma unroll
    for (int r = 0; r < 4; r++) o4[r] = f2b(accO[dt][r]);
    *(u16x4*)(ob + dt * 16 + g * 4) = o4;
  }
}

// ---------------- O partial reduce: Ob = bf16(op0 + op1) ----------------
__global__ __launch_bounds__(256) void ored_k(const uint16_t* __restrict__ op0,
                                              const uint16_t* __restrict__ op1,
                                              uint16_t* __restrict__ Ob) {
  int i = (blockIdx.x * 256 + threadIdx.x) * 4;
  u16x4 a = *(const u16x4*)(op0 + i);
  u16x4 b = *(const u16x4*)(op1 + i);
  u16x4 o;
#pragma unroll
  for (int j = 0; j < 4; j++) o[j] = f2b(b2f(a[j]) + b2f(b[j]));
  *(u16x4*)(Ob + i) = o;
}

// ---------------- LayerNorm over rows of 1024 fp32, optional bf16 copy ----------------
template<int WB>
__global__ __launch_bounds__(256) void ln_k(const float* __restrict__ X,
                                            const float* __restrict__ G,
                                            const float* __restrict__ Bt,
                                            float* __restrict__ Yf,
                                            uint16_t* __restrict__ Yb) {
  const int row = blockIdx.x, t = threadIdx.x;
  const int lane = t & 63, w = t >> 6;
  const size_t base = (size_t)row * 1024 + t * 4;
  f32x4 x = *(const f32x4*)(X + base);
  float s  = x[0] + x[1] + x[2] + x[3];
  float s2 = x[0] * x[0] + x[1] * x[1] + x[2] * x[2] + x[3] * x[3];
#pragma unroll
  for (int o = 1; o < 64; o <<= 1) {
    s  += __shfl_xor(s,  o, 64);
    s2 += __shfl_xor(s2, o, 64);
  }
  __shared__ float red[8];
  if (lane == 0) { red[w] = s; red[4 + w] = s2; }
  __syncthreads();
  s  = red[0] + red[1] + red[2] + red[3];
  s2 = red[4] + red[5] + red[6] + red[7];
  const float mean = s * (1.0f / 1024.0f);
  const float rstd = rsqrtf(s2 * (1.0f / 1024.0f) - mean * mean + 1e-5f);
  f32x4 gv = *(const f32x4*)(G + t * 4);
  f32x4 bv = *(const f32x4*)(Bt + t * 4);
  f32x4 y;
#pragma unroll
  for (int i = 0; i < 4; i++) y[i] = (x[i] - mean) * rstd * gv[i] + bv[i];
  *(f32x4*)(Yf + base) = y;
  if constexpr (WB) {
    u16x4 o;
#pragma unroll
    for (int i = 0; i < 4; i++) o[i] = f2b(y[i]);
    *(u16x4*)(Yb + base) = o;
  }
}

// ---------------- host ----------------
extern "C" void kernel_launch(void* const* d_in, const int* in_sizes, int n_in,
                              void* d_out, int out_size, void* d_ws, size_t ws_size,
                              hipStream_t stream) {
  (void)in_sizes; (void)n_in; (void)out_size;
  const float* id_x = (const float*)d_in[0];
  const float* side = (const float*)d_in[1];
  const float* Wq  = (const float*)d_in[3];
  const float* bq  = (const float*)d_in[4];
  const float* Wk  = (const float*)d_in[5];
  const float* bk  = (const float*)d_in[6];
  const float* Wv  = (const float*)d_in[7];
  const float* bv  = (const float*)d_in[8];
  const float* sWq = (const float*)d_in[9];
  const float* sbq = (const float*)d_in[10];
  const float* sWk = (const float*)d_in[11];
  const float* sbk = (const float*)d_in[12];
  const float* Wo  = (const float*)d_in[13];
  const float* bo  = (const float*)d_in[14];
  const float* W1  = (const float*)d_in[15];
  const float* b1  = (const float*)d_in[16];
  const float* W2  = (const float*)d_in[17];
  const float* b2  = (const float*)d_in[18];
  const float* g1  = (const float*)d_in[19];
  const float* be1 = (const float*)d_in[20];
  const float* g2  = (const float*)d_in[21];
  const float* be2 = (const float*)d_in[22];

  char* ws = (char*)d_ws;
  const size_t oWT   = 0;                       // 10x 1024x1024 bf16 = 20,971,520
  const size_t oBias = 20971520;                // 7168 f32 = 28,672
  const size_t oZP   = 21000192;                // 3*65536 f32 = 786,432
  const size_t oLZ   = 21786624;                // 3*32768 f32 = 393,216
  const size_t oC    = 22179840;                // 4 MB: xb -> op0
  const size_t oD    = 26374144;                // 8 MB: sdb -> op1 | Ob
  const size_t oE    = 34762752;                // 32 MB
  const size_t total = oE + 33554432;           // 68,317,184
  if (ws_size < total) return;

  uint16_t* WT    = (uint16_t*)(ws + oWT);
  float*    biasc = (float*)(ws + oBias);
  float*    zp    = (float*)(ws + oZP);
  float*    lz    = (float*)(ws + oLZ);
  uint16_t* xb    = (uint16_t*)(ws + oC);
  uint16_t* op0   = (uint16_t*)(ws + oC);          // aliases xb (dead post-proj)
  uint16_t* sdb   = (uint16_t*)(ws + oD);
  uint16_t* op1   = (uint16_t*)(ws + oD);          // aliases sdb (dead post-proj)
  uint16_t* Ob    = (uint16_t*)(ws + oD + 4194304);
  char* E = ws + oE;
  uint16_t* qkv  = (uint16_t*)(E);                  // 12 MB
  uint16_t* sqk0 = (uint16_t*)(E + 12582912);       // 8 MB
  uint16_t* sqk1 = (uint16_t*)(E + 20971520);       // 8 MB
  uint16_t* vTp  = (uint16_t*)(E + 29360128);       // 4 MB
  // post-attention aliases (qkv/sqk/vT dead after attn_o):
  float*    x1   = (float*)(E);                     // 8 MB
  float*    x1n  = (float*)(E + 8388608);           // 8 MB
  uint16_t* x1nb = (uint16_t*)(E + 16777216);       // 4 MB
  uint16_t* hb   = (uint16_t*)(E + 20971520);       // 4 MB
  float*    x2   = (float*)(E + 25165824);          // 8 MB

  biascat_k<<<28, 256, 0, stream>>>(bq, bk, bv, sbq, sbk, biasc);
  wtrans_all<<<dim3(32, 32, 10), dim3(32, 8), 0, stream>>>(
      Wq, Wk, Wv, sWq, sWk, sWq + 1048576, sWk + 1048576, Wo, W1, W2, WT);

  f2b_k<<<2048, 256, 0, stream>>>(id_x, xb, 2097152);
  f2b_k<<<4096, 256, 0, stream>>>(side, sdb, 4194304);

  proj_k<<<896, 256, 0, stream>>>(xb, sdb, WT, biasc, qkv, sqk0, sqk1, vTp);

  attn_z<<<1024, 256, 0, stream>>>(qkv, sqk0, sqk1, zp);
  zred_k<<<384, 256, 0, stream>>>(zp, lz);
  attn_o<<<1024, 256, 0, stream>>>(qkv, sqk0, sqk1, vTp, lz, op0);
  ored_k<<<2048, 256, 0, stream>>>(op0, op0 + 2097152, Ob);

  gemm64_k<EPI_RES><<<dim3(8, 32), 256, 0, stream>>>(Ob, 1024, WT + 7340032, bo, id_x, x1, 1024);
  ln_k<1><<<2048, 256, 0, stream>>>(x1, g1, be1, x1n, x1nb);
  gemm64_k<EPI_GELU><<<dim3(8, 32), 256, 0, stream>>>(x1nb, 1024, WT + 8388608, b1, nullptr, hb, 1024);
  gemm64_k<EPI_RES><<<dim3(8, 32), 256, 0, stream>>>(hb, 1024, WT + 9437184, b2, x1n, x2, 1024);
  ln_k<0><<<2048, 256, 0, stream>>>(x2, g2, be2, (float*)d_out, nullptr);
}